// Round 1
// baseline (3402.428 us; speedup 1.0000x reference)
//
#include <hip/hip_runtime.h>
#include <hip/hip_bf16.h>

// RWKV forward, MI355X gfx950.
// All 7 matmuls/layer via bf16 MFMA (16x16x32), m97-style 128x128 tile with
// global_load_lds(16B) staging + xor-swizzled LDS to avoid ds_read_b128 bank
// conflicts. WKV scan: 1 thread per (b,c) chain, software prefetch.

#define LNUM 4
#define BSZ  4
#define TSZ  2048
#define CSZ  1024
#define FFND 4096
#define MROWS (BSZ*TSZ)
#define EPSF 1e-5f

typedef __hip_bfloat16 bf16;
typedef __bf16 bf16x8 __attribute__((ext_vector_type(8)));
typedef float f32x4 __attribute__((ext_vector_type(4)));

#define BM 128
#define BN 128
#define BK 64

__device__ __forceinline__ void async_copy16(const void* g, void* l) {
    __builtin_amdgcn_global_load_lds((const __attribute__((address_space(1))) void*)g,
                                     (__attribute__((address_space(3))) void*)l, 16, 0, 0);
}

// C[M,N] = A[M,K] * Bw[N,K]^T, A/Bw bf16 row-major. MODE epilogues:
// 0: out bf16 = acc          1: out bf16 = sigmoid(acc)
// 2: out f32 += acc          3: out bf16 = relu(acc)^2
// 4: out f32 = sigmoid(acc)  5: out f32 += aux*acc
template<int MODE>
__launch_bounds__(256)
__global__ void gemm_bt(const bf16* __restrict__ A, const bf16* __restrict__ Bw,
                        void* __restrict__ outp, const float* __restrict__ aux,
                        int K, int N)
{
    __shared__ __align__(16) __bf16 sA[BM*BK];
    __shared__ __align__(16) __bf16 sB[BN*BK];
    const int tid  = threadIdx.x;
    const int lane = tid & 63;
    const int wid  = tid >> 6;     // 4 waves: 2x2 of 64x64
    const int wm   = wid >> 1;
    const int wn   = wid & 1;
    const size_t bm0 = (size_t)blockIdx.x * BM;
    const size_t bn0 = (size_t)blockIdx.y * BN;

    // staging: per call a wave fills 1024B = 8 rows x 64 bf16 (8 lanes/row).
    // LDS chunk (r, cb) holds global chunk (cb ^ (r&7))  -> xor swizzle.
    const int lrow8 = lane >> 3;        // row within 8-row group (== r&7)
    const int cbl   = lane & 7;         // LDS 16B-chunk index within row
    const int cbg   = cbl ^ lrow8;      // global chunk actually fetched

    const bf16* pA[4]; const bf16* pB[4];
#pragma unroll
    for (int i = 0; i < 4; ++i) {
        const int rg = (i*4 + wid) * 8;
        pA[i] = A  + (bm0 + rg + lrow8) * (size_t)K + cbg*8;
        pB[i] = Bw + (bn0 + rg + lrow8) * (size_t)K + cbg*8;
    }

    f32x4 acc[4][4];
#pragma unroll
    for (int a = 0; a < 4; ++a)
#pragma unroll
        for (int b = 0; b < 4; ++b) acc[a][b] = (f32x4){0.f,0.f,0.f,0.f};

    const int q   = lane >> 4;   // quad 0..3 (k-group)
    const int rlo = lane & 15;   // row/col within 16-tile

    const int ktiles = K / BK;
    for (int kt = 0; kt < ktiles; ++kt) {
#pragma unroll
        for (int i = 0; i < 4; ++i) {
            const int rg = (i*4 + wid) * 8;
            async_copy16(pA[i], &sA[rg*BK]);
            async_copy16(pB[i], &sB[rg*BK]);
            pA[i] += BK; pB[i] += BK;
        }
        __syncthreads();   // compiler inserts s_waitcnt vmcnt(0) before barrier
#pragma unroll
        for (int ks = 0; ks < 2; ++ks) {
            bf16x8 aF[4], bF[4];
#pragma unroll
            for (int mt = 0; mt < 4; ++mt) {
                const int r  = wm*64 + mt*16 + rlo;
                const int cb = (ks*4 + q) ^ (r & 7);
                aF[mt] = *(const bf16x8*)&sA[r*BK + cb*8];
            }
#pragma unroll
            for (int nt = 0; nt < 4; ++nt) {
                const int r  = wn*64 + nt*16 + rlo;
                const int cb = (ks*4 + q) ^ (r & 7);
                bF[nt] = *(const bf16x8*)&sB[r*BK + cb*8];
            }
#pragma unroll
            for (int mt = 0; mt < 4; ++mt)
#pragma unroll
                for (int nt = 0; nt < 4; ++nt)
                    acc[mt][nt] = __builtin_amdgcn_mfma_f32_16x16x32_bf16(
                        aF[mt], bF[nt], acc[mt][nt], 0, 0, 0);
        }
        __syncthreads();
    }

    // C/D layout: col = lane&15, row = (lane>>4)*4 + reg   [m89/m91 verified]
#pragma unroll
    for (int mt = 0; mt < 4; ++mt) {
#pragma unroll
        for (int nt = 0; nt < 4; ++nt) {
            const size_t col = bn0 + wn*64 + nt*16 + rlo;
#pragma unroll
            for (int i = 0; i < 4; ++i) {
                const size_t row = bm0 + wm*64 + mt*16 + q*4 + i;
                const size_t idx = row * (size_t)N + col;
                const float v = acc[mt][nt][i];
                if (MODE == 0) {
                    ((bf16*)outp)[idx] = __float2bfloat16(v);
                } else if (MODE == 1) {
                    ((bf16*)outp)[idx] = __float2bfloat16(1.f/(1.f+__expf(-v)));
                } else if (MODE == 2) {
                    ((float*)outp)[idx] += v;
                } else if (MODE == 3) {
                    const float t = fmaxf(v, 0.f);
                    ((bf16*)outp)[idx] = __float2bfloat16(t*t);
                } else if (MODE == 4) {
                    ((float*)outp)[idx] = 1.f/(1.f+__expf(-v));
                } else {
                    ((float*)outp)[idx] += aux[idx] * v;
                }
            }
        }
    }
}

// Fused LayerNorm + time_shift + token mixes. Block = one (b,t) row, 256 thr x 4 ch.
// Recomputes LN of row t-1 in-block (prev = 0 at t==0).
template<int NOUT>
__launch_bounds__(256)
__global__ void ln_mix_kernel(const float* __restrict__ x, const float* __restrict__ lnw,
                              const float* __restrict__ mka, const float* __restrict__ mva,
                              const float* __restrict__ mra,
                              bf16* __restrict__ ok, bf16* __restrict__ ov, bf16* __restrict__ orr)
{
    const int bt  = blockIdx.x;
    const int t   = bt % TSZ;
    const int tid = threadIdx.x;
    const float4 xc = ((const float4*)(x + (size_t)bt*CSZ))[tid];
    float4 xp = {0.f,0.f,0.f,0.f};
    const bool hasp = (t != 0);
    if (hasp) xp = ((const float4*)(x + (size_t)(bt-1)*CSZ))[tid];

    float s0 = xc.x+xc.y+xc.z+xc.w;
    float s1 = xc.x*xc.x+xc.y*xc.y+xc.z*xc.z+xc.w*xc.w;
    float s2 = xp.x+xp.y+xp.z+xp.w;
    float s3 = xp.x*xp.x+xp.y*xp.y+xp.z*xp.z+xp.w*xp.w;
#pragma unroll
    for (int off = 32; off > 0; off >>= 1) {
        s0 += __shfl_down(s0, off); s1 += __shfl_down(s1, off);
        s2 += __shfl_down(s2, off); s3 += __shfl_down(s3, off);
    }
    __shared__ float red[4][4];
    if ((tid & 63) == 0) { const int wq = tid >> 6;
        red[wq][0]=s0; red[wq][1]=s1; red[wq][2]=s2; red[wq][3]=s3; }
    __syncthreads();
    s0 = red[0][0]+red[1][0]+red[2][0]+red[3][0];
    s1 = red[0][1]+red[1][1]+red[2][1]+red[3][1];
    s2 = red[0][2]+red[1][2]+red[2][2]+red[3][2];
    s3 = red[0][3]+red[1][3]+red[2][3]+red[3][3];

    const float inv = 1.f/CSZ;
    const float muC = s0*inv;
    const float rsC = rsqrtf(s1*inv - muC*muC + EPSF);
    const float muP = s2*inv;
    const float rsP = rsqrtf(s3*inv - muP*muP + EPSF);

    const int c4 = tid*4;
    const float4 lw = ((const float4*)lnw)[tid];
    const float4 mk = ((const float4*)mka)[tid];
    const float4 mv = (NOUT >= 2) ? ((const float4*)mva)[tid] : lw;
    const float4 mr = (NOUT >= 3) ? ((const float4*)mra)[tid] : lw;

    float hcv[4] = {(xc.x-muC)*rsC*lw.x, (xc.y-muC)*rsC*lw.y,
                    (xc.z-muC)*rsC*lw.z, (xc.w-muC)*rsC*lw.w};
    float hpv[4];
    if (hasp) {
        hpv[0]=(xp.x-muP)*rsP*lw.x; hpv[1]=(xp.y-muP)*rsP*lw.y;
        hpv[2]=(xp.z-muP)*rsP*lw.z; hpv[3]=(xp.w-muP)*rsP*lw.w;
    } else { hpv[0]=hpv[1]=hpv[2]=hpv[3]=0.f; }
    const float mkv[4]={mk.x,mk.y,mk.z,mk.w};
    const float mvv[4]={mv.x,mv.y,mv.z,mv.w};
    const float mrv[4]={mr.x,mr.y,mr.z,mr.w};

    __align__(8) bf16 o0[4], o1[4], o2[4];
#pragma unroll
    for (int j = 0; j < 4; ++j) {
        o0[j] = __float2bfloat16(hcv[j]*mkv[j] + hpv[j]*(1.f-mkv[j]));
        if (NOUT >= 2) o1[j] = __float2bfloat16(hcv[j]*mvv[j] + hpv[j]*(1.f-mvv[j]));
        if (NOUT >= 3) o2[j] = __float2bfloat16(hcv[j]*mrv[j] + hpv[j]*(1.f-mrv[j]));
    }
    *(uint2*)(ok + (size_t)bt*CSZ + c4) = *(const uint2*)o0;
    if (NOUT >= 2) *(uint2*)(ov  + (size_t)bt*CSZ + c4) = *(const uint2*)o1;
    if (NOUT >= 3) *(uint2*)(orr + (size_t)bt*CSZ + c4) = *(const uint2*)o2;
}

// WKV: one thread per (b,c); stabilized recurrence, next-step prefetch.
// Writes rwkv = sigmoid_r * wkv (r already sigmoided by GEMM epilogue).
__launch_bounds__(256)
__global__ void wkv_scan_kernel(const bf16* __restrict__ kb, const bf16* __restrict__ vb,
                                const bf16* __restrict__ rb,
                                const float* __restrict__ td, const float* __restrict__ tf,
                                bf16* __restrict__ outb)
{
    const int id = blockIdx.x * blockDim.x + threadIdx.x;  // 0..BSZ*CSZ-1
    const int b  = id >> 10;
    const int c  = id & (CSZ-1);
    const float w = -__expf(td[c]);
    const float u = tf[c];
    size_t idx = (size_t)b * TSZ * CSZ + c;
    float num = 0.f, den = 0.f, mx = -1e38f;
    float kt = (float)kb[idx], vt = (float)vb[idx], rt = (float)rb[idx];
    for (int t = 0; t < TSZ; ++t) {
        float kn = 0.f, vn = 0.f, rn = 0.f;
        if (t + 1 < TSZ) {
            const size_t nidx = idx + CSZ;
            kn = (float)kb[nidx]; vn = (float)vb[nidx]; rn = (float)rb[nidx];
        }
        const float ku = kt + u;
        const float mo = fmaxf(mx, ku);
        const float e1 = __expf(mx - mo);
        const float e2 = __expf(ku - mo);
        const float outv = (e1*num + e2*vt) / (e1*den + e2);
        const float ms = fmaxf(mx + w, kt);
        const float p1 = __expf(mx + w - ms);
        const float p2 = __expf(kt - ms);
        num = p1*num + p2*vt;
        den = p1*den + p2;
        mx  = ms;
        outb[idx] = __float2bfloat16(rt * outv);
        idx += CSZ;
        kt = kn; vt = vn; rt = rn;
    }
}

__launch_bounds__(256)
__global__ void final_ln_kernel(const float* __restrict__ x, const float* __restrict__ lnw,
                                float* __restrict__ out)
{
    const int bt  = blockIdx.x;
    const int tid = threadIdx.x;
    const float4 xc = ((const float4*)(x + (size_t)bt*CSZ))[tid];
    float s0 = xc.x+xc.y+xc.z+xc.w;
    float s1 = xc.x*xc.x+xc.y*xc.y+xc.z*xc.z+xc.w*xc.w;
#pragma unroll
    for (int off = 32; off > 0; off >>= 1) {
        s0 += __shfl_down(s0, off); s1 += __shfl_down(s1, off);
    }
    __shared__ float red[4][2];
    if ((tid & 63) == 0) { red[tid>>6][0] = s0; red[tid>>6][1] = s1; }
    __syncthreads();
    s0 = red[0][0]+red[1][0]+red[2][0]+red[3][0];
    s1 = red[0][1]+red[1][1]+red[2][1]+red[3][1];
    const float inv = 1.f/CSZ;
    const float mu = s0*inv;
    const float rs = rsqrtf(s1*inv - mu*mu + EPSF);
    const float4 lw = ((const float4*)lnw)[tid];
    float4 o;
    o.x = (xc.x-mu)*rs*lw.x; o.y = (xc.y-mu)*rs*lw.y;
    o.z = (xc.z-mu)*rs*lw.z; o.w = (xc.w-mu)*rs*lw.w;
    ((float4*)(out + (size_t)bt*CSZ))[tid] = o;
}

__global__ void cvt_bf16_kernel(const float* __restrict__ s, bf16* __restrict__ d, int n4)
{
    const int i = blockIdx.x * blockDim.x + threadIdx.x;
    if (i >= n4) return;
    const float4 f = ((const float4*)s)[i];
    __align__(8) bf16 o[4] = {__float2bfloat16(f.x), __float2bfloat16(f.y),
                              __float2bfloat16(f.z), __float2bfloat16(f.w)};
    ((uint2*)d)[i] = *(const uint2*)o;
}

// ---- workspace layout (bytes), total ~218 MiB ----
static constexpr size_t SZ_XF32 = (size_t)MROWS*CSZ*4;   // 32 MiB
static constexpr size_t SZ_ABF  = (size_t)MROWS*CSZ*2;   // 16 MiB
static constexpr size_t OFF_X   = 0;
static constexpr size_t OFF_XK  = OFF_X  + SZ_XF32;
static constexpr size_t OFF_XV  = OFF_XK + SZ_ABF;
static constexpr size_t OFF_XR  = OFF_XV + SZ_ABF;
static constexpr size_t OFF_K   = OFF_XR + SZ_ABF;       // also rr(f32) region
static constexpr size_t OFF_V   = OFF_K  + SZ_ABF;
static constexpr size_t OFF_R   = OFF_V  + SZ_ABF;
static constexpr size_t OFF_KK  = OFF_R  + SZ_ABF;       // bf16 [M,FFN] 64 MiB
static constexpr size_t OFF_W   = OFF_KK + (size_t)MROWS*FFND*2;
static constexpr size_t OFF_WK  = OFF_W;
static constexpr size_t OFF_WV  = OFF_WK + (size_t)CSZ*CSZ*2;
static constexpr size_t OFF_WR  = OFF_WV + (size_t)CSZ*CSZ*2;
static constexpr size_t OFF_WO  = OFF_WR + (size_t)CSZ*CSZ*2;
static constexpr size_t OFF_WCK = OFF_WO + (size_t)CSZ*CSZ*2;
static constexpr size_t OFF_WCV = OFF_WCK + (size_t)FFND*CSZ*2;
static constexpr size_t OFF_WCR = OFF_WCV + (size_t)CSZ*FFND*2;

extern "C" void kernel_launch(void* const* d_in, const int* in_sizes, int n_in,
                              void* d_out, int out_size, void* d_ws, size_t ws_size,
                              hipStream_t stream)
{
    const float* xin   = (const float*)d_in[0];
    const float* ln1w  = (const float*)d_in[1];
    const float* tmixk = (const float*)d_in[2];
    const float* tmixv = (const float*)d_in[3];
    const float* tmixr = (const float*)d_in[4];
    const float* tkw   = (const float*)d_in[5];
    const float* tvw   = (const float*)d_in[6];
    const float* trw   = (const float*)d_in[7];
    const float* tow   = (const float*)d_in[8];
    const float* tdec  = (const float*)d_in[9];
    const float* tfst  = (const float*)d_in[10];
    const float* ln2w  = (const float*)d_in[11];
    const float* cmixk = (const float*)d_in[12];
    const float* cmixr = (const float*)d_in[13];
    const float* ckw   = (const float*)d_in[14];
    const float* cvw   = (const float*)d_in[15];
    const float* crw   = (const float*)d_in[16];
    const float* lnfw  = (const float*)d_in[17];

    char* ws = (char*)d_ws;
    float* xres = (float*)(ws + OFF_X);
    bf16* xk  = (bf16*)(ws + OFF_XK);
    bf16* xv  = (bf16*)(ws + OFF_XV);
    bf16* xr  = (bf16*)(ws + OFF_XR);
    bf16* kb  = (bf16*)(ws + OFF_K);
    bf16* vb  = (bf16*)(ws + OFF_V);
    bf16* rb  = (bf16*)(ws + OFF_R);
    bf16* kkb = (bf16*)(ws + OFF_KK);
    bf16* rwkv = xk;                       // xk dead after k GEMM
    float* rr  = (float*)(ws + OFF_K);     // k/v dead after scan
    bf16* wk  = (bf16*)(ws + OFF_WK);
    bf16* wv  = (bf16*)(ws + OFF_WV);
    bf16* wr  = (bf16*)(ws + OFF_WR);
    bf16* wo  = (bf16*)(ws + OFF_WO);
    bf16* wck = (bf16*)(ws + OFF_WCK);
    bf16* wcv = (bf16*)(ws + OFF_WCV);
    bf16* wcr = (bf16*)(ws + OFF_WCR);

    hipMemcpyAsync(xres, xin, SZ_XF32, hipMemcpyDeviceToDevice, stream);

    const dim3 blk(256);
    const dim3 gC(MROWS/BM, CSZ/BN);    // (64, 8)
    const dim3 gF(MROWS/BM, FFND/BN);   // (64, 32)

    for (int l = 0; l < LNUM; ++l) {
        const size_t oC  = (size_t)l*CSZ;
        const size_t oCC = (size_t)l*CSZ*CSZ;
        const size_t oFC = (size_t)l*FFND*CSZ;
        cvt_bf16_kernel<<<1024, blk, 0, stream>>>(tkw + oCC, wk,  CSZ*CSZ/4);
        cvt_bf16_kernel<<<1024, blk, 0, stream>>>(tvw + oCC, wv,  CSZ*CSZ/4);
        cvt_bf16_kernel<<<1024, blk, 0, stream>>>(trw + oCC, wr,  CSZ*CSZ/4);
        cvt_bf16_kernel<<<1024, blk, 0, stream>>>(tow + oCC, wo,  CSZ*CSZ/4);
        cvt_bf16_kernel<<<4096, blk, 0, stream>>>(ckw + oFC, wck, FFND*CSZ/4);
        cvt_bf16_kernel<<<4096, blk, 0, stream>>>(cvw + oFC, wcv, CSZ*FFND/4);
        cvt_bf16_kernel<<<1024, blk, 0, stream>>>(crw + oCC, wcr, CSZ*CSZ/4);

        // --- TimeMixing ---
        ln_mix_kernel<3><<<MROWS, blk, 0, stream>>>(xres, ln1w + oC,
            tmixk + oC, tmixv + oC, tmixr + oC, xk, xv, xr);
        gemm_bt<0><<<gC, blk, 0, stream>>>(xk, wk, kb, nullptr, CSZ, CSZ);
        gemm_bt<0><<<gC, blk, 0, stream>>>(xv, wv, vb, nullptr, CSZ, CSZ);
        gemm_bt<1><<<gC, blk, 0, stream>>>(xr, wr, rb, nullptr, CSZ, CSZ);
        wkv_scan_kernel<<<(BSZ*CSZ)/256, blk, 0, stream>>>(kb, vb, rb,
            tdec + oC, tfst + oC, rwkv);
        gemm_bt<2><<<gC, blk, 0, stream>>>(rwkv, wo, xres, nullptr, CSZ, CSZ);

        // --- ChannelMixing ---
        ln_mix_kernel<2><<<MROWS, blk, 0, stream>>>(xres, ln2w + oC,
            cmixk + oC, cmixr + oC, nullptr, xk, xv, nullptr);
        gemm_bt<3><<<gF, blk, 0, stream>>>(xk, wck, kkb, nullptr, CSZ, FFND);
        gemm_bt<4><<<gC, blk, 0, stream>>>(xv, wcr, rr, nullptr, CSZ, CSZ);
        gemm_bt<5><<<gC, blk, 0, stream>>>(kkb, wcv, xres, rr, FFND, CSZ);
    }
    final_ln_kernel<<<MROWS, blk, 0, stream>>>(xres, lnfw, (float*)d_out);
}

// Round 2
// 1988.154 us; speedup vs baseline: 1.7114x; 1.7114x over previous
//
#include <hip/hip_runtime.h>
#include <hip/hip_bf16.h>

// RWKV forward, MI355X gfx950.
// GEMMs: bf16 MFMA 16x16x32, 128x128 tile, global_load_lds(16B), xor-swizzled LDS.
// k/v/r GEMMs store TRANSPOSED [B,C,T] so the WKV chunked parallel scan reads
// contiguous-in-t with bf16x8 vector loads. Scan: 32 chunks x 16 channels per
// block (512 thr), local-summary -> sequential chunk combine -> replay.

#define LNUM 4
#define BSZ  4
#define TSZ  2048
#define CSZ  1024
#define FFND 4096
#define MROWS (BSZ*TSZ)
#define EPSF 1e-5f

typedef __hip_bfloat16 bf16;
typedef __bf16 bf16x8 __attribute__((ext_vector_type(8)));
typedef float f32x4 __attribute__((ext_vector_type(4)));

#define BM 128
#define BN 128
#define BK 64

__device__ __forceinline__ void async_copy16(const void* g, void* l) {
    __builtin_amdgcn_global_load_lds((const __attribute__((address_space(1))) void*)g,
                                     (__attribute__((address_space(3))) void*)l, 16, 0, 0);
}

// C[M,N] = A[M,K] * Bw[N,K]^T, A/Bw bf16 row-major. MODE epilogues:
// 2: out f32 += acc              3: out bf16 = relu(acc)^2
// 4: out f32 = sigmoid(acc)      5: out f32 += aux*acc
// 6: out bf16 transposed [B,C,T] 7: out bf16 = sigmoid, transposed [B,C,T]
template<int MODE>
__launch_bounds__(256)
__global__ void gemm_bt(const bf16* __restrict__ A, const bf16* __restrict__ Bw,
                        void* __restrict__ outp, const float* __restrict__ aux,
                        int K, int N)
{
    __shared__ __align__(16) __bf16 sA[BM*BK];
    __shared__ __align__(16) __bf16 sB[BN*BK];
    const int tid  = threadIdx.x;
    const int lane = tid & 63;
    const int wid  = tid >> 6;     // 4 waves: 2x2 of 64x64
    const int wm   = wid >> 1;
    const int wn   = wid & 1;
    const size_t bm0 = (size_t)blockIdx.x * BM;
    const size_t bn0 = (size_t)blockIdx.y * BN;

    // staging: per call a wave fills 1024B = 8 rows x 64 bf16 (8 lanes/row).
    // LDS chunk (r, cb) holds global chunk (cb ^ (r&7))  -> xor swizzle.
    const int lrow8 = lane >> 3;
    const int cbl   = lane & 7;
    const int cbg   = cbl ^ lrow8;

    const bf16* pA[4]; const bf16* pB[4];
#pragma unroll
    for (int i = 0; i < 4; ++i) {
        const int rg = (i*4 + wid) * 8;
        pA[i] = A  + (bm0 + rg + lrow8) * (size_t)K + cbg*8;
        pB[i] = Bw + (bn0 + rg + lrow8) * (size_t)K + cbg*8;
    }

    f32x4 acc[4][4];
#pragma unroll
    for (int a = 0; a < 4; ++a)
#pragma unroll
        for (int b = 0; b < 4; ++b) acc[a][b] = (f32x4){0.f,0.f,0.f,0.f};

    const int q   = lane >> 4;
    const int rlo = lane & 15;

    const int ktiles = K / BK;
    for (int kt = 0; kt < ktiles; ++kt) {
#pragma unroll
        for (int i = 0; i < 4; ++i) {
            const int rg = (i*4 + wid) * 8;
            async_copy16(pA[i], &sA[rg*BK]);
            async_copy16(pB[i], &sB[rg*BK]);
            pA[i] += BK; pB[i] += BK;
        }
        __syncthreads();
#pragma unroll
        for (int ks = 0; ks < 2; ++ks) {
            bf16x8 aF[4], bF[4];
#pragma unroll
            for (int mt = 0; mt < 4; ++mt) {
                const int r  = wm*64 + mt*16 + rlo;
                const int cb = (ks*4 + q) ^ (r & 7);
                aF[mt] = *(const bf16x8*)&sA[r*BK + cb*8];
            }
#pragma unroll
            for (int nt = 0; nt < 4; ++nt) {
                const int r  = wn*64 + nt*16 + rlo;
                const int cb = (ks*4 + q) ^ (r & 7);
                bF[nt] = *(const bf16x8*)&sB[r*BK + cb*8];
            }
#pragma unroll
            for (int mt = 0; mt < 4; ++mt)
#pragma unroll
                for (int nt = 0; nt < 4; ++nt)
                    acc[mt][nt] = __builtin_amdgcn_mfma_f32_16x16x32_bf16(
                        aF[mt], bF[nt], acc[mt][nt], 0, 0, 0);
        }
        __syncthreads();
    }

    // C/D layout: col = lane&15, row = (lane>>4)*4 + reg
    if (MODE == 6 || MODE == 7) {
#pragma unroll
        for (int mt = 0; mt < 4; ++mt) {
#pragma unroll
            for (int nt = 0; nt < 4; ++nt) {
                const int row0 = (int)bm0 + wm*64 + mt*16 + q*4;
                const size_t col = bn0 + wn*64 + nt*16 + rlo;
                const int bb = row0 >> 11;          // / TSZ
                const int t0 = row0 & (TSZ-1);
                __align__(8) bf16 o[4];
#pragma unroll
                for (int i = 0; i < 4; ++i) {
                    float v = acc[mt][nt][i];
                    if (MODE == 7) v = 1.f/(1.f+__expf(-v));
                    o[i] = __float2bfloat16(v);
                }
                *(uint2*)&((bf16*)outp)[((size_t)bb*CSZ + col)*TSZ + t0] = *(const uint2*)o;
            }
        }
    } else {
#pragma unroll
        for (int mt = 0; mt < 4; ++mt) {
#pragma unroll
            for (int nt = 0; nt < 4; ++nt) {
                const size_t col = bn0 + wn*64 + nt*16 + rlo;
#pragma unroll
                for (int i = 0; i < 4; ++i) {
                    const size_t row = bm0 + wm*64 + mt*16 + q*4 + i;
                    const size_t idx = row * (size_t)N + col;
                    const float v = acc[mt][nt][i];
                    if (MODE == 2) {
                        ((float*)outp)[idx] += v;
                    } else if (MODE == 3) {
                        const float t = fmaxf(v, 0.f);
                        ((bf16*)outp)[idx] = __float2bfloat16(t*t);
                    } else if (MODE == 4) {
                        ((float*)outp)[idx] = 1.f/(1.f+__expf(-v));
                    } else {
                        ((float*)outp)[idx] += aux[idx] * v;
                    }
                }
            }
        }
    }
}

// Fused LayerNorm + time_shift + token mixes. Block = one (b,t) row, 256 thr x 4 ch.
template<int NOUT>
__launch_bounds__(256)
__global__ void ln_mix_kernel(const float* __restrict__ x, const float* __restrict__ lnw,
                              const float* __restrict__ mka, const float* __restrict__ mva,
                              const float* __restrict__ mra,
                              bf16* __restrict__ ok, bf16* __restrict__ ov, bf16* __restrict__ orr)
{
    const int bt  = blockIdx.x;
    const int t   = bt % TSZ;
    const int tid = threadIdx.x;
    const float4 xc = ((const float4*)(x + (size_t)bt*CSZ))[tid];
    float4 xp = {0.f,0.f,0.f,0.f};
    const bool hasp = (t != 0);
    if (hasp) xp = ((const float4*)(x + (size_t)(bt-1)*CSZ))[tid];

    float s0 = xc.x+xc.y+xc.z+xc.w;
    float s1 = xc.x*xc.x+xc.y*xc.y+xc.z*xc.z+xc.w*xc.w;
    float s2 = xp.x+xp.y+xp.z+xp.w;
    float s3 = xp.x*xp.x+xp.y*xp.y+xp.z*xp.z+xp.w*xp.w;
#pragma unroll
    for (int off = 32; off > 0; off >>= 1) {
        s0 += __shfl_down(s0, off); s1 += __shfl_down(s1, off);
        s2 += __shfl_down(s2, off); s3 += __shfl_down(s3, off);
    }
    __shared__ float red[4][4];
    if ((tid & 63) == 0) { const int wq = tid >> 6;
        red[wq][0]=s0; red[wq][1]=s1; red[wq][2]=s2; red[wq][3]=s3; }
    __syncthreads();
    s0 = red[0][0]+red[1][0]+red[2][0]+red[3][0];
    s1 = red[0][1]+red[1][1]+red[2][1]+red[3][1];
    s2 = red[0][2]+red[1][2]+red[2][2]+red[3][2];
    s3 = red[0][3]+red[1][3]+red[2][3]+red[3][3];

    const float inv = 1.f/CSZ;
    const float muC = s0*inv;
    const float rsC = rsqrtf(s1*inv - muC*muC + EPSF);
    const float muP = s2*inv;
    const float rsP = rsqrtf(s3*inv - muP*muP + EPSF);

    const int c4 = tid*4;
    const float4 lw = ((const float4*)lnw)[tid];
    const float4 mk = ((const float4*)mka)[tid];
    const float4 mv = (NOUT >= 2) ? ((const float4*)mva)[tid] : lw;
    const float4 mr = (NOUT >= 3) ? ((const float4*)mra)[tid] : lw;

    float hcv[4] = {(xc.x-muC)*rsC*lw.x, (xc.y-muC)*rsC*lw.y,
                    (xc.z-muC)*rsC*lw.z, (xc.w-muC)*rsC*lw.w};
    float hpv[4];
    if (hasp) {
        hpv[0]=(xp.x-muP)*rsP*lw.x; hpv[1]=(xp.y-muP)*rsP*lw.y;
        hpv[2]=(xp.z-muP)*rsP*lw.z; hpv[3]=(xp.w-muP)*rsP*lw.w;
    } else { hpv[0]=hpv[1]=hpv[2]=hpv[3]=0.f; }
    const float mkv[4]={mk.x,mk.y,mk.z,mk.w};
    const float mvv[4]={mv.x,mv.y,mv.z,mv.w};
    const float mrv[4]={mr.x,mr.y,mr.z,mr.w};

    __align__(8) bf16 o0[4], o1[4], o2[4];
#pragma unroll
    for (int j = 0; j < 4; ++j) {
        o0[j] = __float2bfloat16(hcv[j]*mkv[j] + hpv[j]*(1.f-mkv[j]));
        if (NOUT >= 2) o1[j] = __float2bfloat16(hcv[j]*mvv[j] + hpv[j]*(1.f-mvv[j]));
        if (NOUT >= 3) o2[j] = __float2bfloat16(hcv[j]*mrv[j] + hpv[j]*(1.f-mrv[j]));
    }
    *(uint2*)(ok + (size_t)bt*CSZ + c4) = *(const uint2*)o0;
    if (NOUT >= 2) *(uint2*)(ov  + (size_t)bt*CSZ + c4) = *(const uint2*)o1;
    if (NOUT >= 3) *(uint2*)(orr + (size_t)bt*CSZ + c4) = *(const uint2*)o2;
}

// ---- WKV chunked parallel scan ----
// Inputs kT,vT,rT in [B,C,T]. Block: 512 thr = SCK(32) chunks x SCH(16) channels.
// Grid: B*C/SCH = 256 blocks. Chunk length SLEN = T/SCK = 64.
// Unstabilized state N_t = e^w N_{t-1} + e^{k_t} v_t is linear, so:
// pass1 local summary (zero init), sequential combine over 32 summaries,
// pass3 replay from true incoming state, out = sigmoid_r * wkv (r pre-sigmoided).
#define SCH 16
#define SCK 32
#define SLEN (TSZ/SCK)

__launch_bounds__(512)
__global__ void wkv_pscan_kernel(const bf16* __restrict__ kT, const bf16* __restrict__ vT,
                                 const bf16* __restrict__ rT,
                                 const float* __restrict__ td, const float* __restrict__ tf,
                                 bf16* __restrict__ outb)
{
    const int tid = threadIdx.x;
    const int j   = tid >> 4;          // chunk 0..31
    const int ci  = tid & 15;          // channel in group
    const int b   = blockIdx.x / (CSZ/SCH);
    const int c0  = (blockIdx.x % (CSZ/SCH)) * SCH;
    const int c   = c0 + ci;
    const float w = -__expf(td[c]);
    const float u = tf[c];

    const size_t base = ((size_t)b*CSZ + c)*TSZ + j*SLEN;

    // ---- pass 1: local chunk summary from zero init ----
    float num = 0.f, den = 0.f, mx = -1e38f;
    {
        bf16x8 k8 = *(const bf16x8*)(kT + base);
        bf16x8 v8 = *(const bf16x8*)(vT + base);
        for (int t8 = 0; t8 < SLEN/8; ++t8) {
            bf16x8 kn, vn;
            if (t8 + 1 < SLEN/8) {
                kn = *(const bf16x8*)(kT + base + (t8+1)*8);
                vn = *(const bf16x8*)(vT + base + (t8+1)*8);
            }
#pragma unroll
            for (int s = 0; s < 8; ++s) {
                const float kt = (float)k8[s], vt = (float)v8[s];
                const float ms = fmaxf(mx + w, kt);
                const float p1 = __expf(mx + w - ms);
                const float p2 = __expf(kt - ms);
                num = p1*num + p2*vt; den = p1*den + p2; mx = ms;
            }
            k8 = kn; v8 = vn;
        }
    }
    __shared__ float sN[SCK][SCH], sD[SCK][SCH], sM[SCK][SCH];
    sN[j][ci] = num; sD[j][ci] = den; sM[j][ci] = mx;
    __syncthreads();

    // ---- combine: exclusive prefix over chunk summaries (16 threads) ----
    if (tid < SCH) {
        const int cc = c0 + tid;
        const float wLc = -__expf(td[cc]) * (float)SLEN;
        float n = 0.f, d = 0.f, m = -1e38f;
        for (int jj = 0; jj < SCK; ++jj) {
            const float nl = sN[jj][tid], dl = sD[jj][tid], ml = sM[jj][tid];
            sN[jj][tid] = n; sD[jj][tid] = d; sM[jj][tid] = m;   // exclusive prefix
            const float mi = m + wLc;
            const float mo = fmaxf(mi, ml);
            const float e1 = __expf(mi - mo);
            const float e2 = __expf(ml - mo);
            n = e1*n + e2*nl; d = e1*d + e2*dl; m = mo;
        }
    }
    __syncthreads();

    // ---- pass 3: replay from true incoming state, emit outputs ----
    num = sN[j][ci]; den = sD[j][ci]; mx = sM[j][ci];
    {
        bf16x8 k8 = *(const bf16x8*)(kT + base);
        bf16x8 v8 = *(const bf16x8*)(vT + base);
        bf16x8 r8 = *(const bf16x8*)(rT + base);
        size_t oidx = ((size_t)b*TSZ + j*SLEN)*CSZ + c;
        for (int t8 = 0; t8 < SLEN/8; ++t8) {
            bf16x8 kn, vn, rn;
            if (t8 + 1 < SLEN/8) {
                kn = *(const bf16x8*)(kT + base + (t8+1)*8);
                vn = *(const bf16x8*)(vT + base + (t8+1)*8);
                rn = *(const bf16x8*)(rT + base + (t8+1)*8);
            }
#pragma unroll
            for (int s = 0; s < 8; ++s) {
                const float kt = (float)k8[s], vt = (float)v8[s], rt = (float)r8[s];
                const float ku = kt + u;
                const float mo = fmaxf(mx, ku);
                const float e1 = __expf(mx - mo);
                const float e2 = __expf(ku - mo);
                const float outv = (e1*num + e2*vt) / (e1*den + e2);
                const float ms = fmaxf(mx + w, kt);
                const float p1 = __expf(mx + w - ms);
                const float p2 = __expf(kt - ms);
                num = p1*num + p2*vt; den = p1*den + p2; mx = ms;
                outb[oidx] = __float2bfloat16(rt * outv);
                oidx += CSZ;
            }
            k8 = kn; v8 = vn; r8 = rn;
        }
    }
}

__launch_bounds__(256)
__global__ void final_ln_kernel(const float* __restrict__ x, const float* __restrict__ lnw,
                                float* __restrict__ out)
{
    const int bt  = blockIdx.x;
    const int tid = threadIdx.x;
    const float4 xc = ((const float4*)(x + (size_t)bt*CSZ))[tid];
    float s0 = xc.x+xc.y+xc.z+xc.w;
    float s1 = xc.x*xc.x+xc.y*xc.y+xc.z*xc.z+xc.w*xc.w;
#pragma unroll
    for (int off = 32; off > 0; off >>= 1) {
        s0 += __shfl_down(s0, off); s1 += __shfl_down(s1, off);
    }
    __shared__ float red[4][2];
    if ((tid & 63) == 0) { red[tid>>6][0] = s0; red[tid>>6][1] = s1; }
    __syncthreads();
    s0 = red[0][0]+red[1][0]+red[2][0]+red[3][0];
    s1 = red[0][1]+red[1][1]+red[2][1]+red[3][1];
    const float inv = 1.f/CSZ;
    const float mu = s0*inv;
    const float rs = rsqrtf(s1*inv - mu*mu + EPSF);
    const float4 lw = ((const float4*)lnw)[tid];
    float4 o;
    o.x = (xc.x-mu)*rs*lw.x; o.y = (xc.y-mu)*rs*lw.y;
    o.z = (xc.z-mu)*rs*lw.z; o.w = (xc.w-mu)*rs*lw.w;
    ((float4*)(out + (size_t)bt*CSZ))[tid] = o;
}

// One fused per-layer weight conversion (7 tensors -> bf16). Units of 4 elems.
#define N4_CC (CSZ*CSZ/4)
#define N4_FC (FFND*CSZ/4)
__global__ void cvt_weights_kernel(const float* __restrict__ tk, const float* __restrict__ tv,
                                   const float* __restrict__ tr, const float* __restrict__ to,
                                   const float* __restrict__ ck, const float* __restrict__ cv,
                                   const float* __restrict__ cr,
                                   bf16* __restrict__ wk, bf16* __restrict__ wv,
                                   bf16* __restrict__ wr, bf16* __restrict__ wo,
                                   bf16* __restrict__ wck, bf16* __restrict__ wcv,
                                   bf16* __restrict__ wcr)
{
    int i = blockIdx.x * 256 + threadIdx.x;
    const float* s; bf16* d;
    if      (i < 1*N4_CC)          { s = tk; d = wk;  }
    else if (i < 2*N4_CC)          { s = tv; d = wv;  i -= 1*N4_CC; }
    else if (i < 3*N4_CC)          { s = tr; d = wr;  i -= 2*N4_CC; }
    else if (i < 4*N4_CC)          { s = to; d = wo;  i -= 3*N4_CC; }
    else if (i < 4*N4_CC+N4_FC)    { s = ck; d = wck; i -= 4*N4_CC; }
    else if (i < 4*N4_CC+2*N4_FC)  { s = cv; d = wcv; i -= 4*N4_CC+N4_FC; }
    else                           { s = cr; d = wcr; i -= 4*N4_CC+2*N4_FC; }
    const float4 f = ((const float4*)s)[i];
    __align__(8) bf16 o[4] = {__float2bfloat16(f.x), __float2bfloat16(f.y),
                              __float2bfloat16(f.z), __float2bfloat16(f.w)};
    ((uint2*)d)[i] = *(const uint2*)o;
}
#define CVT_TOTAL4 (4*N4_CC + 2*N4_FC + N4_CC)

// ---- workspace layout (bytes), total ~218 MiB ----
static constexpr size_t SZ_XF32 = (size_t)MROWS*CSZ*4;   // 32 MiB
static constexpr size_t SZ_ABF  = (size_t)MROWS*CSZ*2;   // 16 MiB
static constexpr size_t OFF_X   = 0;
static constexpr size_t OFF_XK  = OFF_X  + SZ_XF32;
static constexpr size_t OFF_XV  = OFF_XK + SZ_ABF;
static constexpr size_t OFF_XR  = OFF_XV + SZ_ABF;
static constexpr size_t OFF_K   = OFF_XR + SZ_ABF;       // kT; also rr(f32, 32MB = K+V)
static constexpr size_t OFF_V   = OFF_K  + SZ_ABF;       // vT
static constexpr size_t OFF_R   = OFF_V  + SZ_ABF;       // rT
static constexpr size_t OFF_KK  = OFF_R  + SZ_ABF;       // bf16 [M,FFN] 64 MiB
static constexpr size_t OFF_W   = OFF_KK + (size_t)MROWS*FFND*2;
static constexpr size_t OFF_WK  = OFF_W;
static constexpr size_t OFF_WV  = OFF_WK + (size_t)CSZ*CSZ*2;
static constexpr size_t OFF_WR  = OFF_WV + (size_t)CSZ*CSZ*2;
static constexpr size_t OFF_WO  = OFF_WR + (size_t)CSZ*CSZ*2;
static constexpr size_t OFF_WCK = OFF_WO + (size_t)CSZ*CSZ*2;
static constexpr size_t OFF_WCV = OFF_WCK + (size_t)FFND*CSZ*2;
static constexpr size_t OFF_WCR = OFF_WCV + (size_t)CSZ*FFND*2;

extern "C" void kernel_launch(void* const* d_in, const int* in_sizes, int n_in,
                              void* d_out, int out_size, void* d_ws, size_t ws_size,
                              hipStream_t stream)
{
    const float* xin   = (const float*)d_in[0];
    const float* ln1w  = (const float*)d_in[1];
    const float* tmixk = (const float*)d_in[2];
    const float* tmixv = (const float*)d_in[3];
    const float* tmixr = (const float*)d_in[4];
    const float* tkw   = (const float*)d_in[5];
    const float* tvw   = (const float*)d_in[6];
    const float* trw   = (const float*)d_in[7];
    const float* tow   = (const float*)d_in[8];
    const float* tdec  = (const float*)d_in[9];
    const float* tfst  = (const float*)d_in[10];
    const float* ln2w  = (const float*)d_in[11];
    const float* cmixk = (const float*)d_in[12];
    const float* cmixr = (const float*)d_in[13];
    const float* ckw   = (const float*)d_in[14];
    const float* cvw   = (const float*)d_in[15];
    const float* crw   = (const float*)d_in[16];
    const float* lnfw  = (const float*)d_in[17];

    char* ws = (char*)d_ws;
    float* xres = (float*)(ws + OFF_X);
    bf16* xk  = (bf16*)(ws + OFF_XK);
    bf16* xv  = (bf16*)(ws + OFF_XV);
    bf16* xr  = (bf16*)(ws + OFF_XR);
    bf16* kb  = (bf16*)(ws + OFF_K);       // kT [B,C,T]
    bf16* vb  = (bf16*)(ws + OFF_V);       // vT
    bf16* rb  = (bf16*)(ws + OFF_R);       // rT
    bf16* kkb = (bf16*)(ws + OFF_KK);
    bf16* rwkv = xk;                       // xk dead after k GEMM
    float* rr  = (float*)(ws + OFF_K);     // kT/vT dead after scan
    bf16* wk  = (bf16*)(ws + OFF_WK);
    bf16* wv  = (bf16*)(ws + OFF_WV);
    bf16* wr  = (bf16*)(ws + OFF_WR);
    bf16* wo  = (bf16*)(ws + OFF_WO);
    bf16* wck = (bf16*)(ws + OFF_WCK);
    bf16* wcv = (bf16*)(ws + OFF_WCV);
    bf16* wcr = (bf16*)(ws + OFF_WCR);

    hipMemcpyAsync(xres, xin, SZ_XF32, hipMemcpyDeviceToDevice, stream);

    const dim3 blk(256);
    const dim3 gC(MROWS/BM, CSZ/BN);    // (64, 8)
    const dim3 gF(MROWS/BM, FFND/BN);   // (64, 32)

    for (int l = 0; l < LNUM; ++l) {
        const size_t oC  = (size_t)l*CSZ;
        const size_t oCC = (size_t)l*CSZ*CSZ;
        const size_t oFC = (size_t)l*FFND*CSZ;
        cvt_weights_kernel<<<CVT_TOTAL4/256, blk, 0, stream>>>(
            tkw + oCC, tvw + oCC, trw + oCC, tow + oCC,
            ckw + oFC, cvw + oFC, crw + oCC,
            wk, wv, wr, wo, wck, wcv, wcr);

        // --- TimeMixing ---
        ln_mix_kernel<3><<<MROWS, blk, 0, stream>>>(xres, ln1w + oC,
            tmixk + oC, tmixv + oC, tmixr + oC, xk, xv, xr);
        gemm_bt<6><<<gC, blk, 0, stream>>>(xk, wk, kb, nullptr, CSZ, CSZ);
        gemm_bt<6><<<gC, blk, 0, stream>>>(xv, wv, vb, nullptr, CSZ, CSZ);
        gemm_bt<7><<<gC, blk, 0, stream>>>(xr, wr, rb, nullptr, CSZ, CSZ);
        wkv_pscan_kernel<<<(BSZ*CSZ)/SCH, dim3(512), 0, stream>>>(kb, vb, rb,
            tdec + oC, tfst + oC, rwkv);
        gemm_bt<2><<<gC, blk, 0, stream>>>(rwkv, wo, xres, nullptr, CSZ, CSZ);

        // --- ChannelMixing ---
        ln_mix_kernel<2><<<MROWS, blk, 0, stream>>>(xres, ln2w + oC,
            cmixk + oC, cmixr + oC, nullptr, xk, xv, nullptr);
        gemm_bt<3><<<gF, blk, 0, stream>>>(xk, wck, kkb, nullptr, CSZ, FFND);
        gemm_bt<4><<<gC, blk, 0, stream>>>(xv, wcr, rr, nullptr, CSZ, CSZ);
        gemm_bt<5><<<gC, blk, 0, stream>>>(kkb, wcv, xres, rr, FFND, CSZ);
    }
    final_ln_kernel<<<MROWS, blk, 0, stream>>>(xres, lnfw, (float*)d_out);
}

// Round 3
// 1800.948 us; speedup vs baseline: 1.8892x; 1.1039x over previous
//
#include <hip/hip_runtime.h>
#include <hip/hip_bf16.h>

// RWKV forward, MI355X gfx950.
// GEMMs: bf16 MFMA 16x16x32, 128x128 tile, global_load_lds(16B), xor-swizzled LDS.
// WKV scan: 3-kernel chunked parallel scan (summaries / combine / replay) with
// channels-along-lanes so every global access is a full 128B line.

#define LNUM 4
#define BSZ  4
#define TSZ  2048
#define CSZ  1024
#define FFND 4096
#define MROWS (BSZ*TSZ)
#define EPSF 1e-5f

typedef __hip_bfloat16 bf16;
typedef __bf16 bf16x8 __attribute__((ext_vector_type(8)));
typedef float f32x4 __attribute__((ext_vector_type(4)));

#define BM 128
#define BN 128
#define BK 64

// scan chunking
#define SCK  64
#define SLEN (TSZ/SCK)   // 32

__device__ __forceinline__ void async_copy16(const void* g, void* l) {
    __builtin_amdgcn_global_load_lds((const __attribute__((address_space(1))) void*)g,
                                     (__attribute__((address_space(3))) void*)l, 16, 0, 0);
}

// C[M,N] = A[M,K] * Bw[N,K]^T, A/Bw bf16 row-major. MODE epilogues:
// 0: out bf16 = acc          1: out bf16 = sigmoid(acc)
// 2: out f32 += acc          3: out bf16 = relu(acc)^2
// 4: out f32 = sigmoid(acc)  5: out f32 += aux*acc
template<int MODE>
__launch_bounds__(256)
__global__ void gemm_bt(const bf16* __restrict__ A, const bf16* __restrict__ Bw,
                        void* __restrict__ outp, const float* __restrict__ aux,
                        int K, int N)
{
    __shared__ __align__(16) __bf16 sA[BM*BK];
    __shared__ __align__(16) __bf16 sB[BN*BK];
    const int tid  = threadIdx.x;
    const int lane = tid & 63;
    const int wid  = tid >> 6;     // 4 waves: 2x2 of 64x64
    const int wm   = wid >> 1;
    const int wn   = wid & 1;
    const size_t bm0 = (size_t)blockIdx.x * BM;
    const size_t bn0 = (size_t)blockIdx.y * BN;

    // staging: per call a wave fills 1024B = 8 rows x 64 bf16 (8 lanes/row).
    // LDS chunk (r, cb) holds global chunk (cb ^ (r&7))  -> xor swizzle.
    const int lrow8 = lane >> 3;
    const int cbl   = lane & 7;
    const int cbg   = cbl ^ lrow8;

    const bf16* pA[4]; const bf16* pB[4];
#pragma unroll
    for (int i = 0; i < 4; ++i) {
        const int rg = (i*4 + wid) * 8;
        pA[i] = A  + (bm0 + rg + lrow8) * (size_t)K + cbg*8;
        pB[i] = Bw + (bn0 + rg + lrow8) * (size_t)K + cbg*8;
    }

    f32x4 acc[4][4];
#pragma unroll
    for (int a = 0; a < 4; ++a)
#pragma unroll
        for (int b = 0; b < 4; ++b) acc[a][b] = (f32x4){0.f,0.f,0.f,0.f};

    const int q   = lane >> 4;
    const int rlo = lane & 15;

    const int ktiles = K / BK;
    for (int kt = 0; kt < ktiles; ++kt) {
#pragma unroll
        for (int i = 0; i < 4; ++i) {
            const int rg = (i*4 + wid) * 8;
            async_copy16(pA[i], &sA[rg*BK]);
            async_copy16(pB[i], &sB[rg*BK]);
            pA[i] += BK; pB[i] += BK;
        }
        __syncthreads();
#pragma unroll
        for (int ks = 0; ks < 2; ++ks) {
            bf16x8 aF[4], bF[4];
#pragma unroll
            for (int mt = 0; mt < 4; ++mt) {
                const int r  = wm*64 + mt*16 + rlo;
                const int cb = (ks*4 + q) ^ (r & 7);
                aF[mt] = *(const bf16x8*)&sA[r*BK + cb*8];
            }
#pragma unroll
            for (int nt = 0; nt < 4; ++nt) {
                const int r  = wn*64 + nt*16 + rlo;
                const int cb = (ks*4 + q) ^ (r & 7);
                bF[nt] = *(const bf16x8*)&sB[r*BK + cb*8];
            }
#pragma unroll
            for (int mt = 0; mt < 4; ++mt)
#pragma unroll
                for (int nt = 0; nt < 4; ++nt)
                    acc[mt][nt] = __builtin_amdgcn_mfma_f32_16x16x32_bf16(
                        aF[mt], bF[nt], acc[mt][nt], 0, 0, 0);
        }
        __syncthreads();
    }

    // C/D layout: col = lane&15, row = (lane>>4)*4 + reg
#pragma unroll
    for (int mt = 0; mt < 4; ++mt) {
#pragma unroll
        for (int nt = 0; nt < 4; ++nt) {
            const size_t col = bn0 + wn*64 + nt*16 + rlo;
#pragma unroll
            for (int i = 0; i < 4; ++i) {
                const size_t row = bm0 + wm*64 + mt*16 + q*4 + i;
                const size_t idx = row * (size_t)N + col;
                const float v = acc[mt][nt][i];
                if (MODE == 0) {
                    ((bf16*)outp)[idx] = __float2bfloat16(v);
                } else if (MODE == 1) {
                    ((bf16*)outp)[idx] = __float2bfloat16(1.f/(1.f+__expf(-v)));
                } else if (MODE == 2) {
                    ((float*)outp)[idx] += v;
                } else if (MODE == 3) {
                    const float t = fmaxf(v, 0.f);
                    ((bf16*)outp)[idx] = __float2bfloat16(t*t);
                } else if (MODE == 4) {
                    ((float*)outp)[idx] = 1.f/(1.f+__expf(-v));
                } else {
                    ((float*)outp)[idx] += aux[idx] * v;
                }
            }
        }
    }
}

// Fused LayerNorm + time_shift + token mixes. Block = one (b,t) row, 256 thr x 4 ch.
template<int NOUT>
__launch_bounds__(256)
__global__ void ln_mix_kernel(const float* __restrict__ x, const float* __restrict__ lnw,
                              const float* __restrict__ mka, const float* __restrict__ mva,
                              const float* __restrict__ mra,
                              bf16* __restrict__ ok, bf16* __restrict__ ov, bf16* __restrict__ orr)
{
    const int bt  = blockIdx.x;
    const int t   = bt % TSZ;
    const int tid = threadIdx.x;
    const float4 xc = ((const float4*)(x + (size_t)bt*CSZ))[tid];
    float4 xp = {0.f,0.f,0.f,0.f};
    const bool hasp = (t != 0);
    if (hasp) xp = ((const float4*)(x + (size_t)(bt-1)*CSZ))[tid];

    float s0 = xc.x+xc.y+xc.z+xc.w;
    float s1 = xc.x*xc.x+xc.y*xc.y+xc.z*xc.z+xc.w*xc.w;
    float s2 = xp.x+xp.y+xp.z+xp.w;
    float s3 = xp.x*xp.x+xp.y*xp.y+xp.z*xp.z+xp.w*xp.w;
#pragma unroll
    for (int off = 32; off > 0; off >>= 1) {
        s0 += __shfl_down(s0, off); s1 += __shfl_down(s1, off);
        s2 += __shfl_down(s2, off); s3 += __shfl_down(s3, off);
    }
    __shared__ float red[4][4];
    if ((tid & 63) == 0) { const int wq = tid >> 6;
        red[wq][0]=s0; red[wq][1]=s1; red[wq][2]=s2; red[wq][3]=s3; }
    __syncthreads();
    s0 = red[0][0]+red[1][0]+red[2][0]+red[3][0];
    s1 = red[0][1]+red[1][1]+red[2][1]+red[3][1];
    s2 = red[0][2]+red[1][2]+red[2][2]+red[3][2];
    s3 = red[0][3]+red[1][3]+red[2][3]+red[3][3];

    const float inv = 1.f/CSZ;
    const float muC = s0*inv;
    const float rsC = rsqrtf(s1*inv - muC*muC + EPSF);
    const float muP = s2*inv;
    const float rsP = rsqrtf(s3*inv - muP*muP + EPSF);

    const int c4 = tid*4;
    const float4 lw = ((const float4*)lnw)[tid];
    const float4 mk = ((const float4*)mka)[tid];
    const float4 mv = (NOUT >= 2) ? ((const float4*)mva)[tid] : lw;
    const float4 mr = (NOUT >= 3) ? ((const float4*)mra)[tid] : lw;

    float hcv[4] = {(xc.x-muC)*rsC*lw.x, (xc.y-muC)*rsC*lw.y,
                    (xc.z-muC)*rsC*lw.z, (xc.w-muC)*rsC*lw.w};
    float hpv[4];
    if (hasp) {
        hpv[0]=(xp.x-muP)*rsP*lw.x; hpv[1]=(xp.y-muP)*rsP*lw.y;
        hpv[2]=(xp.z-muP)*rsP*lw.z; hpv[3]=(xp.w-muP)*rsP*lw.w;
    } else { hpv[0]=hpv[1]=hpv[2]=hpv[3]=0.f; }
    const float mkv[4]={mk.x,mk.y,mk.z,mk.w};
    const float mvv[4]={mv.x,mv.y,mv.z,mv.w};
    const float mrv[4]={mr.x,mr.y,mr.z,mr.w};

    __align__(8) bf16 o0[4], o1[4], o2[4];
#pragma unroll
    for (int j = 0; j < 4; ++j) {
        o0[j] = __float2bfloat16(hcv[j]*mkv[j] + hpv[j]*(1.f-mkv[j]));
        if (NOUT >= 2) o1[j] = __float2bfloat16(hcv[j]*mvv[j] + hpv[j]*(1.f-mvv[j]));
        if (NOUT >= 3) o2[j] = __float2bfloat16(hcv[j]*mrv[j] + hpv[j]*(1.f-mrv[j]));
    }
    *(uint2*)(ok + (size_t)bt*CSZ + c4) = *(const uint2*)o0;
    if (NOUT >= 2) *(uint2*)(ov  + (size_t)bt*CSZ + c4) = *(const uint2*)o1;
    if (NOUT >= 3) *(uint2*)(orr + (size_t)bt*CSZ + c4) = *(const uint2*)o2;
}

// ---- WKV 3-kernel chunked parallel scan, channels-along-lanes ----
// k,v,r in [B,T,C]; summaries sN/sD/sM in [B,SCK,C] f32.

// A: per-chunk local summary from zero init.
__launch_bounds__(256)
__global__ void wkv_sum_kernel(const bf16* __restrict__ kb, const bf16* __restrict__ vb,
                               const float* __restrict__ td,
                               float* __restrict__ sN, float* __restrict__ sD,
                               float* __restrict__ sM)
{
    const int j  = blockIdx.x;           // chunk 0..SCK-1
    const int b  = blockIdx.y >> 2;
    const int cg = blockIdx.y & 3;
    const int c  = cg*256 + threadIdx.x;
    const float w = -__expf(td[c]);

    size_t idx = ((size_t)b*TSZ + j*SLEN)*CSZ + c;
    float num = 0.f, den = 0.f, mx = -1e38f;
    float kt = (float)kb[idx], vt = (float)vb[idx];
    for (int t = 0; t < SLEN; ++t) {
        float kn = 0.f, vn = 0.f;
        if (t + 1 < SLEN) {
            kn = (float)kb[idx + CSZ]; vn = (float)vb[idx + CSZ];
        }
        const float ms = fmaxf(mx + w, kt);
        const float p1 = __expf(mx + w - ms);
        const float p2 = __expf(kt - ms);
        num = p1*num + p2*vt; den = p1*den + p2; mx = ms;
        idx += CSZ; kt = kn; vt = vn;
    }
    const size_t sidx = ((size_t)b*SCK + j)*CSZ + c;
    sN[sidx] = num; sD[sidx] = den; sM[sidx] = mx;
}

// B: in-place exclusive prefix over chunk summaries. 4096 threads.
__launch_bounds__(256)
__global__ void wkv_comb_kernel(const float* __restrict__ td,
                                float* __restrict__ sN, float* __restrict__ sD,
                                float* __restrict__ sM)
{
    const int id = blockIdx.x*256 + threadIdx.x;
    const int b  = id >> 10;
    const int c  = id & (CSZ-1);
    const float wL = -__expf(td[c]) * (float)SLEN;
    float n = 0.f, d = 0.f, m = -1e38f;
    size_t idx = (size_t)b*SCK*CSZ + c;
    float nl = sN[idx], dl = sD[idx], ml = sM[idx];
    for (int j = 0; j < SCK; ++j) {
        float nn = 0.f, dn = 0.f, mn = 0.f;
        if (j + 1 < SCK) {
            nn = sN[idx + CSZ]; dn = sD[idx + CSZ]; mn = sM[idx + CSZ];
        }
        sN[idx] = n; sD[idx] = d; sM[idx] = m;   // exclusive prefix
        const float mi = m + wL;
        const float mo = fmaxf(mi, ml);
        const float e1 = __expf(mi - mo);
        const float e2 = __expf(ml - mo);
        n = e1*n + e2*nl; d = e1*d + e2*dl; m = mo;
        idx += CSZ; nl = nn; dl = dn; ml = mn;
    }
}

// C: replay from true incoming state, out = r_sig * wkv.
__launch_bounds__(256)
__global__ void wkv_out_kernel(const bf16* __restrict__ kb, const bf16* __restrict__ vb,
                               const bf16* __restrict__ rb,
                               const float* __restrict__ td, const float* __restrict__ tf,
                               const float* __restrict__ sN, const float* __restrict__ sD,
                               const float* __restrict__ sM,
                               bf16* __restrict__ outb)
{
    const int j  = blockIdx.x;
    const int b  = blockIdx.y >> 2;
    const int cg = blockIdx.y & 3;
    const int c  = cg*256 + threadIdx.x;
    const float w = -__expf(td[c]);
    const float u = tf[c];

    const size_t sidx = ((size_t)b*SCK + j)*CSZ + c;
    float num = sN[sidx], den = sD[sidx], mx = sM[sidx];

    size_t idx = ((size_t)b*TSZ + j*SLEN)*CSZ + c;
    float kt = (float)kb[idx], vt = (float)vb[idx], rt = (float)rb[idx];
    for (int t = 0; t < SLEN; ++t) {
        float kn = 0.f, vn = 0.f, rn = 0.f;
        if (t + 1 < SLEN) {
            kn = (float)kb[idx + CSZ]; vn = (float)vb[idx + CSZ]; rn = (float)rb[idx + CSZ];
        }
        const float ku = kt + u;
        const float mo = fmaxf(mx, ku);
        const float e1 = __expf(mx - mo);
        const float e2 = __expf(ku - mo);
        const float outv = (e1*num + e2*vt) / (e1*den + e2);
        const float ms = fmaxf(mx + w, kt);
        const float p1 = __expf(mx + w - ms);
        const float p2 = __expf(kt - ms);
        num = p1*num + p2*vt; den = p1*den + p2; mx = ms;
        outb[idx] = __float2bfloat16(rt * outv);
        idx += CSZ; kt = kn; vt = vn; rt = rn;
    }
}

__launch_bounds__(256)
__global__ void final_ln_kernel(const float* __restrict__ x, const float* __restrict__ lnw,
                                float* __restrict__ out)
{
    const int bt  = blockIdx.x;
    const int tid = threadIdx.x;
    const float4 xc = ((const float4*)(x + (size_t)bt*CSZ))[tid];
    float s0 = xc.x+xc.y+xc.z+xc.w;
    float s1 = xc.x*xc.x+xc.y*xc.y+xc.z*xc.z+xc.w*xc.w;
#pragma unroll
    for (int off = 32; off > 0; off >>= 1) {
        s0 += __shfl_down(s0, off); s1 += __shfl_down(s1, off);
    }
    __shared__ float red[4][2];
    if ((tid & 63) == 0) { red[tid>>6][0] = s0; red[tid>>6][1] = s1; }
    __syncthreads();
    s0 = red[0][0]+red[1][0]+red[2][0]+red[3][0];
    s1 = red[0][1]+red[1][1]+red[2][1]+red[3][1];
    const float inv = 1.f/CSZ;
    const float mu = s0*inv;
    const float rs = rsqrtf(s1*inv - mu*mu + EPSF);
    const float4 lw = ((const float4*)lnw)[tid];
    float4 o;
    o.x = (xc.x-mu)*rs*lw.x; o.y = (xc.y-mu)*rs*lw.y;
    o.z = (xc.z-mu)*rs*lw.z; o.w = (xc.w-mu)*rs*lw.w;
    ((float4*)(out + (size_t)bt*CSZ))[tid] = o;
}

// One fused per-layer weight conversion (7 tensors -> bf16). Units of 4 elems.
#define N4_CC (CSZ*CSZ/4)
#define N4_FC (FFND*CSZ/4)
__global__ void cvt_weights_kernel(const float* __restrict__ tk, const float* __restrict__ tv,
                                   const float* __restrict__ tr, const float* __restrict__ to,
                                   const float* __restrict__ ck, const float* __restrict__ cv,
                                   const float* __restrict__ cr,
                                   bf16* __restrict__ wk, bf16* __restrict__ wv,
                                   bf16* __restrict__ wr, bf16* __restrict__ wo,
                                   bf16* __restrict__ wck, bf16* __restrict__ wcv,
                                   bf16* __restrict__ wcr)
{
    int i = blockIdx.x * 256 + threadIdx.x;
    const float* s; bf16* d;
    if      (i < 1*N4_CC)          { s = tk; d = wk;  }
    else if (i < 2*N4_CC)          { s = tv; d = wv;  i -= 1*N4_CC; }
    else if (i < 3*N4_CC)          { s = tr; d = wr;  i -= 2*N4_CC; }
    else if (i < 4*N4_CC)          { s = to; d = wo;  i -= 3*N4_CC; }
    else if (i < 4*N4_CC+N4_FC)    { s = ck; d = wck; i -= 4*N4_CC; }
    else if (i < 4*N4_CC+2*N4_FC)  { s = cv; d = wcv; i -= 4*N4_CC+N4_FC; }
    else                           { s = cr; d = wcr; i -= 4*N4_CC+2*N4_FC; }
    const float4 f = ((const float4*)s)[i];
    __align__(8) bf16 o[4] = {__float2bfloat16(f.x), __float2bfloat16(f.y),
                              __float2bfloat16(f.z), __float2bfloat16(f.w)};
    ((uint2*)d)[i] = *(const uint2*)o;
}
#define CVT_TOTAL4 (4*N4_CC + 2*N4_FC + N4_CC)

// ---- workspace layout (bytes), total ~218 MiB ----
static constexpr size_t SZ_XF32 = (size_t)MROWS*CSZ*4;   // 32 MiB
static constexpr size_t SZ_ABF  = (size_t)MROWS*CSZ*2;   // 16 MiB
static constexpr size_t OFF_X   = 0;
static constexpr size_t OFF_XK  = OFF_X  + SZ_XF32;
static constexpr size_t OFF_XV  = OFF_XK + SZ_ABF;
static constexpr size_t OFF_XR  = OFF_XV + SZ_ABF;
static constexpr size_t OFF_K   = OFF_XR + SZ_ABF;       // k; also rr(f32, 32MB = K+V)
static constexpr size_t OFF_V   = OFF_K  + SZ_ABF;       // v
static constexpr size_t OFF_R   = OFF_V  + SZ_ABF;       // r
static constexpr size_t OFF_KK  = OFF_R  + SZ_ABF;       // bf16 [M,FFN] 64 MiB; head reused
                                                         // for scan summaries (3 MiB) during TimeMixing
static constexpr size_t OFF_W   = OFF_KK + (size_t)MROWS*FFND*2;
static constexpr size_t OFF_WK  = OFF_W;
static constexpr size_t OFF_WV  = OFF_WK + (size_t)CSZ*CSZ*2;
static constexpr size_t OFF_WR  = OFF_WV + (size_t)CSZ*CSZ*2;
static constexpr size_t OFF_WO  = OFF_WR + (size_t)CSZ*CSZ*2;
static constexpr size_t OFF_WCK = OFF_WO + (size_t)CSZ*CSZ*2;
static constexpr size_t OFF_WCV = OFF_WCK + (size_t)FFND*CSZ*2;
static constexpr size_t OFF_WCR = OFF_WCV + (size_t)CSZ*FFND*2;

static constexpr size_t SZ_SUM  = (size_t)BSZ*SCK*CSZ*4; // 1 MiB per array

extern "C" void kernel_launch(void* const* d_in, const int* in_sizes, int n_in,
                              void* d_out, int out_size, void* d_ws, size_t ws_size,
                              hipStream_t stream)
{
    const float* xin   = (const float*)d_in[0];
    const float* ln1w  = (const float*)d_in[1];
    const float* tmixk = (const float*)d_in[2];
    const float* tmixv = (const float*)d_in[3];
    const float* tmixr = (const float*)d_in[4];
    const float* tkw   = (const float*)d_in[5];
    const float* tvw   = (const float*)d_in[6];
    const float* trw   = (const float*)d_in[7];
    const float* tow   = (const float*)d_in[8];
    const float* tdec  = (const float*)d_in[9];
    const float* tfst  = (const float*)d_in[10];
    const float* ln2w  = (const float*)d_in[11];
    const float* cmixk = (const float*)d_in[12];
    const float* cmixr = (const float*)d_in[13];
    const float* ckw   = (const float*)d_in[14];
    const float* cvw   = (const float*)d_in[15];
    const float* crw   = (const float*)d_in[16];
    const float* lnfw  = (const float*)d_in[17];

    char* ws = (char*)d_ws;
    float* xres = (float*)(ws + OFF_X);
    bf16* xk  = (bf16*)(ws + OFF_XK);
    bf16* xv  = (bf16*)(ws + OFF_XV);
    bf16* xr  = (bf16*)(ws + OFF_XR);
    bf16* kb  = (bf16*)(ws + OFF_K);       // k [B,T,C]
    bf16* vb  = (bf16*)(ws + OFF_V);       // v
    bf16* rb  = (bf16*)(ws + OFF_R);       // r (sigmoided)
    bf16* kkb = (bf16*)(ws + OFF_KK);
    bf16* rwkv = xk;                       // xk dead after k GEMM
    float* rr  = (float*)(ws + OFF_K);     // k/v dead after scan
    float* sN  = (float*)(ws + OFF_KK);               // kkb dead during TimeMixing
    float* sD  = (float*)(ws + OFF_KK + SZ_SUM);
    float* sM  = (float*)(ws + OFF_KK + 2*SZ_SUM);
    bf16* wk  = (bf16*)(ws + OFF_WK);
    bf16* wv  = (bf16*)(ws + OFF_WV);
    bf16* wr  = (bf16*)(ws + OFF_WR);
    bf16* wo  = (bf16*)(ws + OFF_WO);
    bf16* wck = (bf16*)(ws + OFF_WCK);
    bf16* wcv = (bf16*)(ws + OFF_WCV);
    bf16* wcr = (bf16*)(ws + OFF_WCR);

    hipMemcpyAsync(xres, xin, SZ_XF32, hipMemcpyDeviceToDevice, stream);

    const dim3 blk(256);
    const dim3 gC(MROWS/BM, CSZ/BN);    // (64, 8)
    const dim3 gF(MROWS/BM, FFND/BN);   // (64, 32)
    const dim3 gScan(SCK, BSZ*4);       // (64, 16), 256 thr

    for (int l = 0; l < LNUM; ++l) {
        const size_t oC  = (size_t)l*CSZ;
        const size_t oCC = (size_t)l*CSZ*CSZ;
        const size_t oFC = (size_t)l*FFND*CSZ;
        cvt_weights_kernel<<<CVT_TOTAL4/256, blk, 0, stream>>>(
            tkw + oCC, tvw + oCC, trw + oCC, tow + oCC,
            ckw + oFC, cvw + oFC, crw + oCC,
            wk, wv, wr, wo, wck, wcv, wcr);

        // --- TimeMixing ---
        ln_mix_kernel<3><<<MROWS, blk, 0, stream>>>(xres, ln1w + oC,
            tmixk + oC, tmixv + oC, tmixr + oC, xk, xv, xr);
        gemm_bt<0><<<gC, blk, 0, stream>>>(xk, wk, kb, nullptr, CSZ, CSZ);
        gemm_bt<0><<<gC, blk, 0, stream>>>(xv, wv, vb, nullptr, CSZ, CSZ);
        gemm_bt<1><<<gC, blk, 0, stream>>>(xr, wr, rb, nullptr, CSZ, CSZ);
        wkv_sum_kernel<<<gScan, blk, 0, stream>>>(kb, vb, tdec + oC, sN, sD, sM);
        wkv_comb_kernel<<<(BSZ*CSZ)/256, blk, 0, stream>>>(tdec + oC, sN, sD, sM);
        wkv_out_kernel<<<gScan, blk, 0, stream>>>(kb, vb, rb, tdec + oC, tfst + oC,
            sN, sD, sM, rwkv);
        gemm_bt<2><<<gC, blk, 0, stream>>>(rwkv, wo, xres, nullptr, CSZ, CSZ);

        // --- ChannelMixing ---
        ln_mix_kernel<2><<<MROWS, blk, 0, stream>>>(xres, ln2w + oC,
            cmixk + oC, cmixr + oC, nullptr, xk, xv, nullptr);
        gemm_bt<3><<<gF, blk, 0, stream>>>(xk, wck, kkb, nullptr, CSZ, FFND);
        gemm_bt<4><<<gC, blk, 0, stream>>>(xv, wcr, rr, nullptr, CSZ, CSZ);
        gemm_bt<5><<<gC, blk, 0, stream>>>(kkb, wcv, xres, rr, FFND, CSZ);
    }
    final_ln_kernel<<<MROWS, blk, 0, stream>>>(xres, lnfw, (float*)d_out);
}

// Round 4
// 1667.611 us; speedup vs baseline: 2.0403x; 1.0800x over previous
//
#include <hip/hip_runtime.h>
#include <hip/hip_bf16.h>

// RWKV forward, MI355X gfx950.
// GEMMs: bf16 MFMA 16x16x32, global_load_lds(16B), xor-swizzled LDS.
//   N=4096 GEMM (cm_k): 128x128 tile.  N=1024 GEMMs: 128x64 tile (4+ blocks/CU,
//   2x grid) to fix the 512-block starvation seen in R3. k/v/r merged via grid.z.
// WKV scan: 3-kernel chunked parallel scan, channels-along-lanes.

#define LNUM 4
#define BSZ  4
#define TSZ  2048
#define CSZ  1024
#define FFND 4096
#define MROWS (BSZ*TSZ)
#define EPSF 1e-5f

typedef __hip_bfloat16 bf16;
typedef __bf16 bf16x8 __attribute__((ext_vector_type(8)));
typedef float f32x4 __attribute__((ext_vector_type(4)));

#define BM 128
#define BK 64

// scan chunking
#define SCK  64
#define SLEN (TSZ/SCK)   // 32

__device__ __forceinline__ void async_copy16(const void* g, void* l) {
    __builtin_amdgcn_global_load_lds((const __attribute__((address_space(1))) void*)g,
                                     (__attribute__((address_space(3))) void*)l, 16, 0, 0);
}

// ---- shared GEMM body ----
// C[M,N] = A[M,K] * Bw[N,K]^T, bf16 row-major. TBN=128: 4 waves 2x2 of 64x64.
// TBN=64: 4 waves 4x1 of 32x64. MODE epilogues:
// 2: out f32 += acc              3: out bf16 = relu(acc)^2
// 4: out bf16 = sigmoid(acc)     5: out f32 += (float)auxbf[idx] * acc
template<int MODE, int TBN>
__launch_bounds__(256)
__global__ void gemm_bt(const bf16* __restrict__ A, const bf16* __restrict__ Bw,
                        void* __restrict__ outp, const bf16* __restrict__ aux,
                        int K, int N)
{
    constexpr int MT  = (TBN == 128) ? 4 : 2;   // 16-row tiles per wave
    constexpr int NBI = TBN / 32;               // B staging issues per thread
    __shared__ __align__(16) __bf16 sA[BM*BK];
    __shared__ __align__(16) __bf16 sB[TBN*BK];
    const int tid  = threadIdx.x;
    const int lane = tid & 63;
    const int wid  = tid >> 6;
    const int wmB  = (TBN == 128) ? (wid >> 1) * 64 : wid * 32;  // wave row base
    const int wnB  = (TBN == 128) ? (wid & 1) * 64 : 0;          // wave col base
    const size_t bm0 = (size_t)blockIdx.x * BM;
    const size_t bn0 = (size_t)blockIdx.y * TBN;

    // staging: 8 lanes/row, 8 chunks of 16B per 64-elem row; xor swizzle.
    const int lrow8 = lane >> 3;
    const int cbg   = (lane & 7) ^ lrow8;

    const bf16* pA[4]; const bf16* pB[NBI];
#pragma unroll
    for (int i = 0; i < 4; ++i)
        pA[i] = A + (bm0 + (i*4 + wid)*8 + lrow8) * (size_t)K + cbg*8;
#pragma unroll
    for (int i = 0; i < NBI; ++i)
        pB[i] = Bw + (bn0 + (i*4 + wid)*8 + lrow8) * (size_t)K + cbg*8;

    f32x4 acc[MT][4];
#pragma unroll
    for (int a = 0; a < MT; ++a)
#pragma unroll
        for (int b = 0; b < 4; ++b) acc[a][b] = (f32x4){0.f,0.f,0.f,0.f};

    const int q   = lane >> 4;
    const int rlo = lane & 15;

    const int ktiles = K / BK;
    for (int kt = 0; kt < ktiles; ++kt) {
#pragma unroll
        for (int i = 0; i < 4; ++i) {
            async_copy16(pA[i], &sA[(i*4 + wid)*8*BK]);
            pA[i] += BK;
        }
#pragma unroll
        for (int i = 0; i < NBI; ++i) {
            async_copy16(pB[i], &sB[(i*4 + wid)*8*BK]);
            pB[i] += BK;
        }
        __syncthreads();
#pragma unroll
        for (int ks = 0; ks < 2; ++ks) {
            bf16x8 aF[MT], bF[4];
#pragma unroll
            for (int mt = 0; mt < MT; ++mt) {
                const int r  = wmB + mt*16 + rlo;
                const int cb = (ks*4 + q) ^ (r & 7);
                aF[mt] = *(const bf16x8*)&sA[r*BK + cb*8];
            }
#pragma unroll
            for (int nt = 0; nt < 4; ++nt) {
                const int r  = wnB + nt*16 + rlo;
                const int cb = (ks*4 + q) ^ (r & 7);
                bF[nt] = *(const bf16x8*)&sB[r*BK + cb*8];
            }
#pragma unroll
            for (int mt = 0; mt < MT; ++mt)
#pragma unroll
                for (int nt = 0; nt < 4; ++nt)
                    acc[mt][nt] = __builtin_amdgcn_mfma_f32_16x16x32_bf16(
                        aF[mt], bF[nt], acc[mt][nt], 0, 0, 0);
        }
        __syncthreads();
    }

    // C/D layout: col = lane&15, row = (lane>>4)*4 + reg
#pragma unroll
    for (int mt = 0; mt < MT; ++mt) {
#pragma unroll
        for (int nt = 0; nt < 4; ++nt) {
            const size_t col = bn0 + wnB + nt*16 + rlo;
#pragma unroll
            for (int i = 0; i < 4; ++i) {
                const size_t row = bm0 + wmB + mt*16 + q*4 + i;
                const size_t idx = row * (size_t)N + col;
                const float v = acc[mt][nt][i];
                if (MODE == 2) {
                    ((float*)outp)[idx] += v;
                } else if (MODE == 3) {
                    const float t = fmaxf(v, 0.f);
                    ((bf16*)outp)[idx] = __float2bfloat16(t*t);
                } else if (MODE == 4) {
                    ((bf16*)outp)[idx] = __float2bfloat16(1.f/(1.f+__expf(-v)));
                } else {
                    ((float*)outp)[idx] += (float)aux[idx] * v;
                }
            }
        }
    }
}

// k/v/r GEMMs merged: grid.z selects {A,W,out}; z==2 applies sigmoid.
__launch_bounds__(256)
__global__ void gemm_kvr(const bf16* __restrict__ A0, const bf16* __restrict__ A1,
                         const bf16* __restrict__ A2,
                         const bf16* __restrict__ W0, const bf16* __restrict__ W1,
                         const bf16* __restrict__ W2,
                         bf16* __restrict__ O0, bf16* __restrict__ O1,
                         bf16* __restrict__ O2)
{
    constexpr int TBN = 64, MT = 2, NBI = 2, K = CSZ, N = CSZ;
    const int z = blockIdx.z;
    const bf16* A  = (z == 0) ? A0 : (z == 1) ? A1 : A2;
    const bf16* Bw = (z == 0) ? W0 : (z == 1) ? W1 : W2;
    bf16* outp     = (z == 0) ? O0 : (z == 1) ? O1 : O2;

    __shared__ __align__(16) __bf16 sA[BM*BK];
    __shared__ __align__(16) __bf16 sB[TBN*BK];
    const int tid  = threadIdx.x;
    const int lane = tid & 63;
    const int wid  = tid >> 6;
    const int wmB  = wid * 32;
    const size_t bm0 = (size_t)blockIdx.x * BM;
    const size_t bn0 = (size_t)blockIdx.y * TBN;

    const int lrow8 = lane >> 3;
    const int cbg   = (lane & 7) ^ lrow8;

    const bf16* pA[4]; const bf16* pB[NBI];
#pragma unroll
    for (int i = 0; i < 4; ++i)
        pA[i] = A + (bm0 + (i*4 + wid)*8 + lrow8) * (size_t)K + cbg*8;
#pragma unroll
    for (int i = 0; i < NBI; ++i)
        pB[i] = Bw + (bn0 + (i*4 + wid)*8 + lrow8) * (size_t)K + cbg*8;

    f32x4 acc[MT][4];
#pragma unroll
    for (int a = 0; a < MT; ++a)
#pragma unroll
        for (int b = 0; b < 4; ++b) acc[a][b] = (f32x4){0.f,0.f,0.f,0.f};

    const int q   = lane >> 4;
    const int rlo = lane & 15;

    for (int kt = 0; kt < K/BK; ++kt) {
#pragma unroll
        for (int i = 0; i < 4; ++i) {
            async_copy16(pA[i], &sA[(i*4 + wid)*8*BK]);
            pA[i] += BK;
        }
#pragma unroll
        for (int i = 0; i < NBI; ++i) {
            async_copy16(pB[i], &sB[(i*4 + wid)*8*BK]);
            pB[i] += BK;
        }
        __syncthreads();
#pragma unroll
        for (int ks = 0; ks < 2; ++ks) {
            bf16x8 aF[MT], bF[4];
#pragma unroll
            for (int mt = 0; mt < MT; ++mt) {
                const int r  = wmB + mt*16 + rlo;
                const int cb = (ks*4 + q) ^ (r & 7);
                aF[mt] = *(const bf16x8*)&sA[r*BK + cb*8];
            }
#pragma unroll
            for (int nt = 0; nt < 4; ++nt) {
                const int r  = nt*16 + rlo;
                const int cb = (ks*4 + q) ^ (r & 7);
                bF[nt] = *(const bf16x8*)&sB[r*BK + cb*8];
            }
#pragma unroll
            for (int mt = 0; mt < MT; ++mt)
#pragma unroll
                for (int nt = 0; nt < 4; ++nt)
                    acc[mt][nt] = __builtin_amdgcn_mfma_f32_16x16x32_bf16(
                        aF[mt], bF[nt], acc[mt][nt], 0, 0, 0);
        }
        __syncthreads();
    }

#pragma unroll
    for (int mt = 0; mt < MT; ++mt) {
#pragma unroll
        for (int nt = 0; nt < 4; ++nt) {
            const size_t col = bn0 + nt*16 + rlo;
#pragma unroll
            for (int i = 0; i < 4; ++i) {
                const size_t row = bm0 + wmB + mt*16 + q*4 + i;
                float v = acc[mt][nt][i];
                if (z == 2) v = 1.f/(1.f+__expf(-v));
                ((bf16*)outp)[row * (size_t)N + col] = __float2bfloat16(v);
            }
        }
    }
}

// Fused LayerNorm + time_shift + token mixes. Block = one (b,t) row, 256 thr x 4 ch.
template<int NOUT>
__launch_bounds__(256)
__global__ void ln_mix_kernel(const float* __restrict__ x, const float* __restrict__ lnw,
                              const float* __restrict__ mka, const float* __restrict__ mva,
                              const float* __restrict__ mra,
                              bf16* __restrict__ ok, bf16* __restrict__ ov, bf16* __restrict__ orr)
{
    const int bt  = blockIdx.x;
    const int t   = bt % TSZ;
    const int tid = threadIdx.x;
    const float4 xc = ((const float4*)(x + (size_t)bt*CSZ))[tid];
    float4 xp = {0.f,0.f,0.f,0.f};
    const bool hasp = (t != 0);
    if (hasp) xp = ((const float4*)(x + (size_t)(bt-1)*CSZ))[tid];

    float s0 = xc.x+xc.y+xc.z+xc.w;
    float s1 = xc.x*xc.x+xc.y*xc.y+xc.z*xc.z+xc.w*xc.w;
    float s2 = xp.x+xp.y+xp.z+xp.w;
    float s3 = xp.x*xp.x+xp.y*xp.y+xp.z*xp.z+xp.w*xp.w;
#pragma unroll
    for (int off = 32; off > 0; off >>= 1) {
        s0 += __shfl_down(s0, off); s1 += __shfl_down(s1, off);
        s2 += __shfl_down(s2, off); s3 += __shfl_down(s3, off);
    }
    __shared__ float red[4][4];
    if ((tid & 63) == 0) { const int wq = tid >> 6;
        red[wq][0]=s0; red[wq][1]=s1; red[wq][2]=s2; red[wq][3]=s3; }
    __syncthreads();
    s0 = red[0][0]+red[1][0]+red[2][0]+red[3][0];
    s1 = red[0][1]+red[1][1]+red[2][1]+red[3][1];
    s2 = red[0][2]+red[1][2]+red[2][2]+red[3][2];
    s3 = red[0][3]+red[1][3]+red[2][3]+red[3][3];

    const float inv = 1.f/CSZ;
    const float muC = s0*inv;
    const float rsC = rsqrtf(s1*inv - muC*muC + EPSF);
    const float muP = s2*inv;
    const float rsP = rsqrtf(s3*inv - muP*muP + EPSF);

    const int c4 = tid*4;
    const float4 lw = ((const float4*)lnw)[tid];
    const float4 mk = ((const float4*)mka)[tid];
    const float4 mv = (NOUT >= 2) ? ((const float4*)mva)[tid] : lw;
    const float4 mr = (NOUT >= 3) ? ((const float4*)mra)[tid] : lw;

    float hcv[4] = {(xc.x-muC)*rsC*lw.x, (xc.y-muC)*rsC*lw.y,
                    (xc.z-muC)*rsC*lw.z, (xc.w-muC)*rsC*lw.w};
    float hpv[4];
    if (hasp) {
        hpv[0]=(xp.x-muP)*rsP*lw.x; hpv[1]=(xp.y-muP)*rsP*lw.y;
        hpv[2]=(xp.z-muP)*rsP*lw.z; hpv[3]=(xp.w-muP)*rsP*lw.w;
    } else { hpv[0]=hpv[1]=hpv[2]=hpv[3]=0.f; }
    const float mkv[4]={mk.x,mk.y,mk.z,mk.w};
    const float mvv[4]={mv.x,mv.y,mv.z,mv.w};
    const float mrv[4]={mr.x,mr.y,mr.z,mr.w};

    __align__(8) bf16 o0[4], o1[4], o2[4];
#pragma unroll
    for (int j = 0; j < 4; ++j) {
        o0[j] = __float2bfloat16(hcv[j]*mkv[j] + hpv[j]*(1.f-mkv[j]));
        if (NOUT >= 2) o1[j] = __float2bfloat16(hcv[j]*mvv[j] + hpv[j]*(1.f-mvv[j]));
        if (NOUT >= 3) o2[j] = __float2bfloat16(hcv[j]*mrv[j] + hpv[j]*(1.f-mrv[j]));
    }
    *(uint2*)(ok + (size_t)bt*CSZ + c4) = *(const uint2*)o0;
    if (NOUT >= 2) *(uint2*)(ov  + (size_t)bt*CSZ + c4) = *(const uint2*)o1;
    if (NOUT >= 3) *(uint2*)(orr + (size_t)bt*CSZ + c4) = *(const uint2*)o2;
}

// ---- WKV 3-kernel chunked parallel scan, channels-along-lanes ----
__launch_bounds__(256)
__global__ void wkv_sum_kernel(const bf16* __restrict__ kb, const bf16* __restrict__ vb,
                               const float* __restrict__ td,
                               float* __restrict__ sN, float* __restrict__ sD,
                               float* __restrict__ sM)
{
    const int j  = blockIdx.x;
    const int b  = blockIdx.y >> 2;
    const int cg = blockIdx.y & 3;
    const int c  = cg*256 + threadIdx.x;
    const float w = -__expf(td[c]);

    size_t idx = ((size_t)b*TSZ + j*SLEN)*CSZ + c;
    float num = 0.f, den = 0.f, mx = -1e38f;
    float kt = (float)kb[idx], vt = (float)vb[idx];
    for (int t = 0; t < SLEN; ++t) {
        float kn = 0.f, vn = 0.f;
        if (t + 1 < SLEN) {
            kn = (float)kb[idx + CSZ]; vn = (float)vb[idx + CSZ];
        }
        const float ms = fmaxf(mx + w, kt);
        const float p1 = __expf(mx + w - ms);
        const float p2 = __expf(kt - ms);
        num = p1*num + p2*vt; den = p1*den + p2; mx = ms;
        idx += CSZ; kt = kn; vt = vn;
    }
    const size_t sidx = ((size_t)b*SCK + j)*CSZ + c;
    sN[sidx] = num; sD[sidx] = den; sM[sidx] = mx;
}

__launch_bounds__(256)
__global__ void wkv_comb_kernel(const float* __restrict__ td,
                                float* __restrict__ sN, float* __restrict__ sD,
                                float* __restrict__ sM)
{
    const int id = blockIdx.x*256 + threadIdx.x;
    const int b  = id >> 10;
    const int c  = id & (CSZ-1);
    const float wL = -__expf(td[c]) * (float)SLEN;
    float n = 0.f, d = 0.f, m = -1e38f;
    size_t idx = (size_t)b*SCK*CSZ + c;
    float nl = sN[idx], dl = sD[idx], ml = sM[idx];
    for (int j = 0; j < SCK; ++j) {
        float nn = 0.f, dn = 0.f, mn = 0.f;
        if (j + 1 < SCK) {
            nn = sN[idx + CSZ]; dn = sD[idx + CSZ]; mn = sM[idx + CSZ];
        }
        sN[idx] = n; sD[idx] = d; sM[idx] = m;
        const float mi = m + wL;
        const float mo = fmaxf(mi, ml);
        const float e1 = __expf(mi - mo);
        const float e2 = __expf(ml - mo);
        n = e1*n + e2*nl; d = e1*d + e2*dl; m = mo;
        idx += CSZ; nl = nn; dl = dn; ml = mn;
    }
}

__launch_bounds__(256)
__global__ void wkv_out_kernel(const bf16* __restrict__ kb, const bf16* __restrict__ vb,
                               const bf16* __restrict__ rb,
                               const float* __restrict__ td, const float* __restrict__ tf,
                               const float* __restrict__ sN, const float* __restrict__ sD,
                               const float* __restrict__ sM,
                               bf16* __restrict__ outb)
{
    const int j  = blockIdx.x;
    const int b  = blockIdx.y >> 2;
    const int cg = blockIdx.y & 3;
    const int c  = cg*256 + threadIdx.x;
    const float w = -__expf(td[c]);
    const float u = tf[c];

    const size_t sidx = ((size_t)b*SCK + j)*CSZ + c;
    float num = sN[sidx], den = sD[sidx], mx = sM[sidx];

    size_t idx = ((size_t)b*TSZ + j*SLEN)*CSZ + c;
    float kt = (float)kb[idx], vt = (float)vb[idx], rt = (float)rb[idx];
    for (int t = 0; t < SLEN; ++t) {
        float kn = 0.f, vn = 0.f, rn = 0.f;
        if (t + 1 < SLEN) {
            kn = (float)kb[idx + CSZ]; vn = (float)vb[idx + CSZ]; rn = (float)rb[idx + CSZ];
        }
        const float ku = kt + u;
        const float mo = fmaxf(mx, ku);
        const float e1 = __expf(mx - mo);
        const float e2 = __expf(ku - mo);
        const float outv = (e1*num + e2*vt) / (e1*den + e2);
        const float ms = fmaxf(mx + w, kt);
        const float p1 = __expf(mx + w - ms);
        const float p2 = __expf(kt - ms);
        num = p1*num + p2*vt; den = p1*den + p2; mx = ms;
        outb[idx] = __float2bfloat16(rt * outv);
        idx += CSZ; kt = kn; vt = vn; rt = rn;
    }
}

__launch_bounds__(256)
__global__ void final_ln_kernel(const float* __restrict__ x, const float* __restrict__ lnw,
                                float* __restrict__ out)
{
    const int bt  = blockIdx.x;
    const int tid = threadIdx.x;
    const float4 xc = ((const float4*)(x + (size_t)bt*CSZ))[tid];
    float s0 = xc.x+xc.y+xc.z+xc.w;
    float s1 = xc.x*xc.x+xc.y*xc.y+xc.z*xc.z+xc.w*xc.w;
#pragma unroll
    for (int off = 32; off > 0; off >>= 1) {
        s0 += __shfl_down(s0, off); s1 += __shfl_down(s1, off);
    }
    __shared__ float red[4][2];
    if ((tid & 63) == 0) { red[tid>>6][0] = s0; red[tid>>6][1] = s1; }
    __syncthreads();
    s0 = red[0][0]+red[1][0]+red[2][0]+red[3][0];
    s1 = red[0][1]+red[1][1]+red[2][1]+red[3][1];
    const float inv = 1.f/CSZ;
    const float mu = s0*inv;
    const float rs = rsqrtf(s1*inv - mu*mu + EPSF);
    const float4 lw = ((const float4*)lnw)[tid];
    float4 o;
    o.x = (xc.x-mu)*rs*lw.x; o.y = (xc.y-mu)*rs*lw.y;
    o.z = (xc.z-mu)*rs*lw.z; o.w = (xc.w-mu)*rs*lw.w;
    ((float4*)(out + (size_t)bt*CSZ))[tid] = o;
}

// One fused per-layer weight conversion (7 tensors -> bf16). Units of 4 elems.
#define N4_CC (CSZ*CSZ/4)
#define N4_FC (FFND*CSZ/4)
__global__ void cvt_weights_kernel(const float* __restrict__ tk, const float* __restrict__ tv,
                                   const float* __restrict__ tr, const float* __restrict__ to,
                                   const float* __restrict__ ck, const float* __restrict__ cv,
                                   const float* __restrict__ cr,
                                   bf16* __restrict__ wk, bf16* __restrict__ wv,
                                   bf16* __restrict__ wr, bf16* __restrict__ wo,
                                   bf16* __restrict__ wck, bf16* __restrict__ wcv,
                                   bf16* __restrict__ wcr)
{
    int i = blockIdx.x * 256 + threadIdx.x;
    const float* s; bf16* d;
    if      (i < 1*N4_CC)          { s = tk; d = wk;  }
    else if (i < 2*N4_CC)          { s = tv; d = wv;  i -= 1*N4_CC; }
    else if (i < 3*N4_CC)          { s = tr; d = wr;  i -= 2*N4_CC; }
    else if (i < 4*N4_CC)          { s = to; d = wo;  i -= 3*N4_CC; }
    else if (i < 4*N4_CC+N4_FC)    { s = ck; d = wck; i -= 4*N4_CC; }
    else if (i < 4*N4_CC+2*N4_FC)  { s = cv; d = wcv; i -= 4*N4_CC+N4_FC; }
    else                           { s = cr; d = wcr; i -= 4*N4_CC+2*N4_FC; }
    const float4 f = ((const float4*)s)[i];
    __align__(8) bf16 o[4] = {__float2bfloat16(f.x), __float2bfloat16(f.y),
                              __float2bfloat16(f.z), __float2bfloat16(f.w)};
    ((uint2*)d)[i] = *(const uint2*)o;
}
#define CVT_TOTAL4 (4*N4_CC + 2*N4_FC + N4_CC)

// ---- workspace layout (bytes), total ~218 MiB ----
static constexpr size_t SZ_XF32 = (size_t)MROWS*CSZ*4;   // 32 MiB
static constexpr size_t SZ_ABF  = (size_t)MROWS*CSZ*2;   // 16 MiB
static constexpr size_t OFF_X   = 0;
static constexpr size_t OFF_XK  = OFF_X  + SZ_XF32;
static constexpr size_t OFF_XV  = OFF_XK + SZ_ABF;
static constexpr size_t OFF_XR  = OFF_XV + SZ_ABF;
static constexpr size_t OFF_K   = OFF_XR + SZ_ABF;       // k; later rr (bf16)
static constexpr size_t OFF_V   = OFF_K  + SZ_ABF;       // v
static constexpr size_t OFF_R   = OFF_V  + SZ_ABF;       // r
static constexpr size_t OFF_KK  = OFF_R  + SZ_ABF;       // bf16 [M,FFN] 64 MiB; head reused
                                                         // for scan summaries during TimeMixing
static constexpr size_t OFF_W   = OFF_KK + (size_t)MROWS*FFND*2;
static constexpr size_t OFF_WK  = OFF_W;
static constexpr size_t OFF_WV  = OFF_WK + (size_t)CSZ*CSZ*2;
static constexpr size_t OFF_WR  = OFF_WV + (size_t)CSZ*CSZ*2;
static constexpr size_t OFF_WO  = OFF_WR + (size_t)CSZ*CSZ*2;
static constexpr size_t OFF_WCK = OFF_WO + (size_t)CSZ*CSZ*2;
static constexpr size_t OFF_WCV = OFF_WCK + (size_t)FFND*CSZ*2;
static constexpr size_t OFF_WCR = OFF_WCV + (size_t)CSZ*FFND*2;

static constexpr size_t SZ_SUM  = (size_t)BSZ*SCK*CSZ*4; // 1 MiB per array

extern "C" void kernel_launch(void* const* d_in, const int* in_sizes, int n_in,
                              void* d_out, int out_size, void* d_ws, size_t ws_size,
                              hipStream_t stream)
{
    const float* xin   = (const float*)d_in[0];
    const float* ln1w  = (const float*)d_in[1];
    const float* tmixk = (const float*)d_in[2];
    const float* tmixv = (const float*)d_in[3];
    const float* tmixr = (const float*)d_in[4];
    const float* tkw   = (const float*)d_in[5];
    const float* tvw   = (const float*)d_in[6];
    const float* trw   = (const float*)d_in[7];
    const float* tow   = (const float*)d_in[8];
    const float* tdec  = (const float*)d_in[9];
    const float* tfst  = (const float*)d_in[10];
    const float* ln2w  = (const float*)d_in[11];
    const float* cmixk = (const float*)d_in[12];
    const float* cmixr = (const float*)d_in[13];
    const float* ckw   = (const float*)d_in[14];
    const float* cvw   = (const float*)d_in[15];
    const float* crw   = (const float*)d_in[16];
    const float* lnfw  = (const float*)d_in[17];

    char* ws = (char*)d_ws;
    float* xres = (float*)(ws + OFF_X);
    bf16* xk  = (bf16*)(ws + OFF_XK);
    bf16* xv  = (bf16*)(ws + OFF_XV);
    bf16* xr  = (bf16*)(ws + OFF_XR);
    bf16* kb  = (bf16*)(ws + OFF_K);       // k [B,T,C]
    bf16* vb  = (bf16*)(ws + OFF_V);       // v
    bf16* rb  = (bf16*)(ws + OFF_R);       // r (sigmoided)
    bf16* kkb = (bf16*)(ws + OFF_KK);
    bf16* rwkv = xk;                       // xk dead after k GEMM
    bf16* rr  = (bf16*)(ws + OFF_K);       // k dead after scan; rr bf16
    float* sN  = (float*)(ws + OFF_KK);    // kkb dead during TimeMixing
    float* sD  = (float*)(ws + OFF_KK + SZ_SUM);
    float* sM  = (float*)(ws + OFF_KK + 2*SZ_SUM);
    bf16* wk  = (bf16*)(ws + OFF_WK);
    bf16* wv  = (bf16*)(ws + OFF_WV);
    bf16* wr  = (bf16*)(ws + OFF_WR);
    bf16* wo  = (bf16*)(ws + OFF_WO);
    bf16* wck = (bf16*)(ws + OFF_WCK);
    bf16* wcv = (bf16*)(ws + OFF_WCV);
    bf16* wcr = (bf16*)(ws + OFF_WCR);

    hipMemcpyAsync(xres, xin, SZ_XF32, hipMemcpyDeviceToDevice, stream);

    const dim3 blk(256);
    const dim3 gKVR(MROWS/BM, CSZ/64, 3);   // (64, 16, 3) = 3072 blocks
    const dim3 gC64(MROWS/BM, CSZ/64);      // (64, 16) = 1024 blocks
    const dim3 gF(MROWS/BM, FFND/128);      // (64, 32) = 2048 blocks
    const dim3 gScan(SCK, BSZ*4);           // (64, 16)

    for (int l = 0; l < LNUM; ++l) {
        const size_t oC  = (size_t)l*CSZ;
        const size_t oCC = (size_t)l*CSZ*CSZ;
        const size_t oFC = (size_t)l*FFND*CSZ;
        cvt_weights_kernel<<<CVT_TOTAL4/256, blk, 0, stream>>>(
            tkw + oCC, tvw + oCC, trw + oCC, tow + oCC,
            ckw + oFC, cvw + oFC, crw + oCC,
            wk, wv, wr, wo, wck, wcv, wcr);

        // --- TimeMixing ---
        ln_mix_kernel<3><<<MROWS, blk, 0, stream>>>(xres, ln1w + oC,
            tmixk + oC, tmixv + oC, tmixr + oC, xk, xv, xr);
        gemm_kvr<<<gKVR, blk, 0, stream>>>(xk, xv, xr, wk, wv, wr, kb, vb, rb);
        wkv_sum_kernel<<<gScan, blk, 0, stream>>>(kb, vb, tdec + oC, sN, sD, sM);
        wkv_comb_kernel<<<(BSZ*CSZ)/256, blk, 0, stream>>>(tdec + oC, sN, sD, sM);
        wkv_out_kernel<<<gScan, blk, 0, stream>>>(kb, vb, rb, tdec + oC, tfst + oC,
            sN, sD, sM, rwkv);
        gemm_bt<2,64><<<gC64, blk, 0, stream>>>(rwkv, wo, xres, nullptr, CSZ, CSZ);

        // --- ChannelMixing ---
        ln_mix_kernel<2><<<MROWS, blk, 0, stream>>>(xres, ln2w + oC,
            cmixk + oC, cmixr + oC, nullptr, xk, xv, nullptr);
        gemm_bt<3,128><<<gF, blk, 0, stream>>>(xk, wck, kkb, nullptr, CSZ, FFND);
        gemm_bt<4,64><<<gC64, blk, 0, stream>>>(xv, wcr, rr, nullptr, CSZ, CSZ);
        gemm_bt<5,64><<<gC64, blk, 0, stream>>>(kkb, wcv, xres, rr, FFND, CSZ);
    }
    final_ln_kernel<<<MROWS, blk, 0, stream>>>(xres, lnfw, (float*)d_out);
}